// Round 1
// baseline (3648.518 us; speedup 1.0000x reference)
//
#include <hip/hip_runtime.h>
#include <hip/hip_bf16.h>
#include <stdint.h>

#define NQ 32
#define NCLS 5
#define SHOT 5
#define NIMG 57          // 32 query + 25 support
#define P1 7056          // 84*84
#define P2 1764          // 42*42
#define P3 441           // 21*21
#define MM (SHOT*P3)     // 2205
#define EPSB 1e-5f
#define SLOPE 0.2f

typedef __attribute__((ext_vector_type(8))) short short8;
typedef __attribute__((ext_vector_type(4))) float f32x4;

__device__ inline float ldf(const float* p) { return *p; }
__device__ inline float ldf(const __hip_bfloat16* p) { return __bfloat162float(*p); }

// ---------------- conv1: NCHW fp32 input (3ch) -> channels-last bf16 [img][p][64] ----------
__global__ __launch_bounds__(256) void conv1_k(const float* __restrict__ in1,
                                               const float* __restrict__ in2,
                                               const float* __restrict__ w,
                                               __hip_bfloat16* __restrict__ out)
{
    __shared__ float wl[27 * 65];          // [k=cin*9+tap][cout], pad 65
    int b = blockIdx.x;
    int img = b / 441;
    int r = b % 441;                       // 21x21 tiles of 4x4 pixels
    int ty = r / 21, tx = r % 21;
    int y0 = ty * 4, x0 = tx * 4;
    int lane = threadIdx.x & 63, wv = threadIdx.x >> 6;
    for (int i = threadIdx.x; i < 64 * 27; i += 256) {
        int co = i / 27, kk = i - co * 27;
        wl[kk * 65 + co] = w[i];
    }
    const float* in = (img < NQ) ? in1 + (size_t)img * 3 * P1
                                 : in2 + (size_t)(img - NQ) * 3 * P1;
    int x = x0 + wv;
    __syncthreads();
    float acc[4] = {0.f, 0.f, 0.f, 0.f};
    #pragma unroll
    for (int cin = 0; cin < 3; ++cin) {
        float v[6][3];
        #pragma unroll
        for (int ry = 0; ry < 6; ++ry) {
            int yy = y0 - 1 + ry;
            #pragma unroll
            for (int cx = 0; cx < 3; ++cx) {
                int xx = x - 1 + cx;
                bool okl = (yy >= 0) & (yy < 84) & (xx >= 0) & (xx < 84);
                v[ry][cx] = okl ? in[cin * P1 + yy * 84 + xx] : 0.f;
            }
        }
        #pragma unroll
        for (int ky = 0; ky < 3; ++ky)
            #pragma unroll
            for (int kx = 0; kx < 3; ++kx) {
                float wt = wl[(cin * 9 + ky * 3 + kx) * 65 + lane];
                #pragma unroll
                for (int i = 0; i < 4; ++i) acc[i] = fmaf(v[i + ky][kx], wt, acc[i]);
            }
    }
    #pragma unroll
    for (int i = 0; i < 4; ++i)
        out[((size_t)img * P1 + (size_t)(y0 + i) * 84 + x) * 64 + lane] = __float2bfloat16(acc[i]);
}

// ---------------- conv 64->64 channels-last fp32, S=42 or 21 ----------------
__global__ __launch_bounds__(256) void conv64_k(const float* __restrict__ in,
                                                const float* __restrict__ w,
                                                float* __restrict__ out, int S)
{
    __shared__ float wl[144 * 65];         // [k=tap*16+cl][cout], pad 65
    int nt = (S + 3) >> 2;
    int b = blockIdx.x;
    int img = b / (nt * nt);
    int r = b % (nt * nt);
    int ty = r / nt, tx = r % nt;
    int y0 = ty * 4, x0 = tx * 4;
    int lane = threadIdx.x & 63, wv = threadIdx.x >> 6;
    int x = x0 + wv;
    const float* ib = in + (size_t)img * S * S * 64;
    int off[6][3];
    bool okm[6][3];
    #pragma unroll
    for (int ry = 0; ry < 6; ++ry) {
        int yy = y0 - 1 + ry;
        #pragma unroll
        for (int cx = 0; cx < 3; ++cx) {
            int xx = x - 1 + cx;
            okm[ry][cx] = (yy >= 0) & (yy < S) & (xx >= 0) & (xx < S);
            off[ry][cx] = (yy * S + xx) * 64;
        }
    }
    float acc[4] = {0.f, 0.f, 0.f, 0.f};
    for (int ch = 0; ch < 4; ++ch) {       // 16-cin chunks
        __syncthreads();
        for (int i = threadIdx.x; i < 9216; i += 256) {
            int co = i / 144, kk = i - co * 144;
            int cl = kk / 9, tap = kk - cl * 9;
            wl[(tap * 16 + cl) * 65 + co] = w[(size_t)co * 576 + ch * 144 + kk];
        }
        __syncthreads();
        #pragma unroll
        for (int cl4 = 0; cl4 < 4; ++cl4) {
            int cin = ch * 16 + cl4 * 4;
            float4 v[6][3];
            #pragma unroll
            for (int ry = 0; ry < 6; ++ry)
                #pragma unroll
                for (int cx = 0; cx < 3; ++cx) {
                    float4 z = {0.f, 0.f, 0.f, 0.f};
                    v[ry][cx] = okm[ry][cx] ? *(const float4*)(ib + off[ry][cx] + cin) : z;
                }
            #pragma unroll
            for (int ky = 0; ky < 3; ++ky)
                #pragma unroll
                for (int kx = 0; kx < 3; ++kx) {
                    int kb = ((ky * 3 + kx) * 16 + cl4 * 4) * 65 + lane;
                    float w0 = wl[kb], w1 = wl[kb + 65], w2 = wl[kb + 130], w3 = wl[kb + 195];
                    #pragma unroll
                    for (int i = 0; i < 4; ++i) {
                        float4 t = v[i + ky][kx];
                        acc[i] = fmaf(t.x, w0, acc[i]);
                        acc[i] = fmaf(t.y, w1, acc[i]);
                        acc[i] = fmaf(t.z, w2, acc[i]);
                        acc[i] = fmaf(t.w, w3, acc[i]);
                    }
                }
        }
    }
    if (x < S) {
        #pragma unroll
        for (int i = 0; i < 4; ++i) {
            int yy = y0 + i;
            if (yy < S)
                out[((size_t)img * S * S + (size_t)yy * S + x) * 64 + lane] = acc[i];
        }
    }
}

// ---------------- BN stats: per (group, channel) sum / sumsq via atomics ----------------
template <typename T>
__global__ __launch_bounds__(256) void stats_k(const T* __restrict__ x, int P,
                                               float* __restrict__ sums)
{
    int g = blockIdx.x / 64;               // 64 blocks per group
    int bg = blockIdx.x % 64;
    int lane = threadIdx.x & 63, wvr = threadIdx.x >> 6;
    int img0 = (g == 0) ? 0 : NQ + (g - 1) * SHOT;
    int ni = (g == 0) ? NQ : SHOT;
    float s = 0.f, s2 = 0.f;
    for (int im = 0; im < ni; ++im) {
        const T* base = x + (size_t)(img0 + im) * P * 64;
        for (int p = bg * 4 + wvr; p < P; p += 256) {
            float v = ldf(base + (size_t)p * 64 + lane);
            s += v;
            s2 = fmaf(v, v, s2);
        }
    }
    atomicAdd(&sums[(g * 64 + lane) * 2 + 0], s);
    atomicAdd(&sums[(g * 64 + lane) * 2 + 1], s2);
}

// fold (mean, invstd, gamma, beta) -> (a, b): y = x*a + b
__global__ void finalize_k(const float* __restrict__ sums, float* __restrict__ ms,
                           const float* __restrict__ gamma, const float* __restrict__ beta, int P)
{
    int i = blockIdx.x * blockDim.x + threadIdx.x;
    if (i >= 6 * 64) return;
    int g = i >> 6, c = i & 63;
    float cnt = (float)((g == 0 ? NQ : SHOT) * P);
    float mean = sums[i * 2] / cnt;
    float var = sums[i * 2 + 1] / cnt - mean * mean;
    float a = rsqrtf(var + EPSB) * gamma[c];
    ms[i * 2] = a;
    ms[i * 2 + 1] = fmaf(-mean, a, beta[c]);
}

// ---------------- BN + LeakyReLU + 2x2 maxpool ----------------
template <typename T>
__global__ __launch_bounds__(256) void bnpool_k(const T* __restrict__ x, const float* __restrict__ ms,
                                                float* __restrict__ out, int Win)
{
    int Wout = Win >> 1, Pout = Wout * Wout;
    size_t idx = (size_t)blockIdx.x * 256 + threadIdx.x;
    size_t total = (size_t)NIMG * Pout * 64;
    if (idx >= total) return;
    int c = (int)(idx & 63);
    size_t t = idx >> 6;
    int p = (int)(t % Pout);
    int img = (int)(t / Pout);
    int y = p / Wout, xo = p - y * Wout;
    int g = (img < NQ) ? 0 : 1 + (img - NQ) / SHOT;
    float a = ms[(g * 64 + c) * 2], bb = ms[(g * 64 + c) * 2 + 1];
    const T* base = x + (((size_t)img * Win + 2 * y) * Win + 2 * xo) * 64 + c;
    float mx = -3.4e38f;
    #pragma unroll
    for (int dy = 0; dy < 2; ++dy)
        #pragma unroll
        for (int dx = 0; dx < 2; ++dx) {
            float v = ldf(base + ((size_t)dy * Win + dx) * 64);
            v = fmaf(v, a, bb);
            v = v >= 0.f ? v : SLOPE * v;
            mx = fmaxf(mx, v);
        }
    out[idx] = mx;
}

// ---------------- BN + LeakyReLU (elementwise, stage 3) ----------------
__global__ __launch_bounds__(256) void bnact_k(const float* __restrict__ x, const float* __restrict__ ms,
                                               float* __restrict__ out)
{
    size_t idx = (size_t)blockIdx.x * 256 + threadIdx.x;
    size_t total = (size_t)NIMG * P3 * 64;
    if (idx >= total) return;
    int c = (int)(idx & 63);
    int img = (int)(idx >> 6) / P3;
    int g = (img < NQ) ? 0 : 1 + (img - NQ) / SHOT;
    float v = fmaf(x[idx], ms[(g * 64 + c) * 2], ms[(g * 64 + c) * 2 + 1]);
    out[idx] = v >= 0.f ? v : SLOPE * v;
}

// ---------------- BN4 + LeakyReLU + per-pixel L2-normalize -> bf16 ----------------
__global__ __launch_bounds__(256) void bnnorm_k(const float* __restrict__ x, const float* __restrict__ ms,
                                                __hip_bfloat16* __restrict__ out)
{
    int lane = threadIdx.x & 63, wvr = threadIdx.x >> 6;
    int pix = blockIdx.x * 4 + wvr;        // one wave per pixel
    if (pix >= NIMG * P3) return;
    int img = pix / P3;
    int g = (img < NQ) ? 0 : 1 + (img - NQ) / SHOT;
    float v = fmaf(x[(size_t)pix * 64 + lane], ms[(g * 64 + lane) * 2], ms[(g * 64 + lane) * 2 + 1]);
    v = v >= 0.f ? v : SLOPE * v;
    float ss = v * v;
    #pragma unroll
    for (int d = 32; d > 0; d >>= 1) ss += __shfl_xor(ss, d, 64);
    out[(size_t)pix * 64 + lane] = __float2bfloat16(v * rsqrtf(ss));
}

// ---------------- similarity: MFMA bf16, per-lane running top-3, shfl merge ----------------
__device__ inline void ins3(float v, float& t0, float& t1, float& t2)
{
    if (v > t2) {
        if (v > t1) {
            t2 = t1;
            if (v > t0) { t1 = t0; t0 = v; }
            else t1 = v;
        } else t2 = v;
    }
}

__global__ __launch_bounds__(256) void sim_k(const __hip_bfloat16* __restrict__ fhat,
                                             float* __restrict__ out)
{
    __shared__ __align__(16) unsigned short sl[64 * 72];   // 64 m-rows, 72-ushort stride
    int t = blockIdx.x;
    int qb = t % 7;
    int n = (t / 7) % NCLS;
    int bq = t / (7 * NCLS);
    int lane = threadIdx.x & 63, wv = threadIdx.x >> 6;
    int col = lane & 15, quad = lane >> 4;
    // A fragments: 16 q rows of this wave's q-tile, K=64 in two halves
    int q = qb * 64 + wv * 16 + col;
    int qc = q < P3 ? q : P3 - 1;
    const unsigned short* qp = (const unsigned short*)fhat + ((size_t)bq * P3 + qc) * 64;
    short8 a0 = *(const short8*)(qp + quad * 8);
    short8 a1 = *(const short8*)(qp + 32 + quad * 8);
    const unsigned short* sp = (const unsigned short*)fhat + (size_t)(NQ + n * SHOT) * P3 * 64;
    float t0[4], t1[4], t2[4];
    #pragma unroll
    for (int i = 0; i < 4; ++i) { t0[i] = -3.4e38f; t1[i] = -3.4e38f; t2[i] = -3.4e38f; }
    for (int mc = 0; mc < 35; ++mc) {
        int m0 = mc * 64;
        __syncthreads();
        #pragma unroll
        for (int pass = 0; pass < 2; ++pass) {
            int row = (threadIdx.x >> 3) + pass * 32;
            int cc = (threadIdx.x & 7) * 8;
            int m = m0 + row;
            short8 vv = {0, 0, 0, 0, 0, 0, 0, 0};
            if (m < MM) vv = *(const short8*)(sp + (size_t)m * 64 + cc);
            *(short8*)(sl + row * 72 + cc) = vv;
        }
        __syncthreads();
        #pragma unroll
        for (int mt = 0; mt < 4; ++mt) {
            const unsigned short* sr = sl + (mt * 16 + col) * 72;
            short8 b0 = *(const short8*)(sr + quad * 8);
            short8 b1 = *(const short8*)(sr + 32 + quad * 8);
            f32x4 acc = {0.f, 0.f, 0.f, 0.f};
            acc = __builtin_amdgcn_mfma_f32_16x16x32_bf16(a0, b0, acc, 0, 0, 0);
            acc = __builtin_amdgcn_mfma_f32_16x16x32_bf16(a1, b1, acc, 0, 0, 0);
            int m = m0 + mt * 16 + col;
            if (m < MM) {
                ins3(acc[0], t0[0], t1[0], t2[0]);
                ins3(acc[1], t0[1], t1[1], t2[1]);
                ins3(acc[2], t0[2], t1[2], t2[2]);
                ins3(acc[3], t0[3], t1[3], t2[3]);
            }
        }
    }
    // merge top-3 across the 16 lanes of each quad-group (same C rows)
    #pragma unroll
    for (int d = 1; d < 16; d <<= 1) {
        #pragma unroll
        for (int i = 0; i < 4; ++i) {
            float u0 = __shfl_xor(t0[i], d, 64);
            float u1 = __shfl_xor(t1[i], d, 64);
            float u2 = __shfl_xor(t2[i], d, 64);
            ins3(u0, t0[i], t1[i], t2[i]);
            ins3(u1, t0[i], t1[i], t2[i]);
            ins3(u2, t0[i], t1[i], t2[i]);
        }
    }
    if (col == 0) {
        float s = 0.f;
        int q0 = qb * 64 + wv * 16 + quad * 4;
        #pragma unroll
        for (int i = 0; i < 4; ++i)
            if (q0 + i < P3) s += t0[i] + t1[i] + t2[i];
        atomicAdd(&out[bq * NCLS + n], s);
    }
}

extern "C" void kernel_launch(void* const* d_in, const int* in_sizes, int n_in,
                              void* d_out, int out_size, void* d_ws, size_t ws_size,
                              hipStream_t stream)
{
    const float* input1 = (const float*)d_in[0];
    const float* input2 = (const float*)d_in[1];
    const float* w1 = (const float*)d_in[2];
    const float* g1 = (const float*)d_in[3];
    const float* b1 = (const float*)d_in[4];
    const float* w2 = (const float*)d_in[5];
    const float* g2 = (const float*)d_in[6];
    const float* b2 = (const float*)d_in[7];
    const float* w3 = (const float*)d_in[8];
    const float* g3 = (const float*)d_in[9];
    const float* b3 = (const float*)d_in[10];
    const float* w4 = (const float*)d_in[11];
    const float* g4 = (const float*)d_in[12];
    const float* b4 = (const float*)d_in[13];
    float* out = (float*)d_out;

    char* w8 = (char*)d_ws;
    const size_t oA = 0;                       // 51,480,576 B region A
    const size_t oB = 51480576;                // 25,740,288 B region B
    const size_t oSums = oB + 25740288;        // 12,288 B (4 stages x 768 floats)
    const size_t oMs = oSums + 12288;          // 12,288 B
    if (ws_size < oMs + 12288) return;

    __hip_bfloat16* conv1raw = (__hip_bfloat16*)(w8 + oA);          // [57][7056][64] bf16
    float* conv2raw = (float*)(w8 + oA);                            // reuse A: [57][1764][64] f32
    __hip_bfloat16* fhat = (__hip_bfloat16*)(w8 + oA);              // reuse A: [57][441][64] bf16
    float* pooled1 = (float*)(w8 + oB);                             // [57][1764][64] f32
    float* pooled2 = (float*)(w8 + oB);                             // reuse B: [57][441][64]
    float* conv3raw = (float*)(w8 + oB + 6435072);
    float* act3 = (float*)(w8 + oB + 2 * 6435072);
    float* conv4raw = (float*)(w8 + oB + 3 * 6435072);
    float* sums = (float*)(w8 + oSums);
    float* ms = (float*)(w8 + oMs);

    hipMemsetAsync(d_out, 0, (size_t)out_size * sizeof(float), stream);
    hipMemsetAsync(sums, 0, 12288, stream);

    // stage 1: conv1 -> stats -> BN+LReLU+pool (84 -> 42)
    conv1_k<<<NIMG * 441, 256, 0, stream>>>(input1, input2, w1, conv1raw);
    stats_k<__hip_bfloat16><<<6 * 64, 256, 0, stream>>>(conv1raw, P1, sums + 0);
    finalize_k<<<2, 256, 0, stream>>>(sums + 0, ms + 0, g1, b1, P1);
    bnpool_k<__hip_bfloat16><<<25137, 256, 0, stream>>>(conv1raw, ms + 0, pooled1, 84);
    // stage 2: conv2 -> stats -> BN+LReLU+pool (42 -> 21)
    conv64_k<<<NIMG * 121, 256, 0, stream>>>(pooled1, w2, conv2raw, 42);
    stats_k<float><<<6 * 64, 256, 0, stream>>>(conv2raw, P2, sums + 768);
    finalize_k<<<2, 256, 0, stream>>>(sums + 768, ms + 768, g2, b2, P2);
    bnpool_k<float><<<6285, 256, 0, stream>>>(conv2raw, ms + 768, pooled2, 42);
    // stage 3: conv3 -> stats -> BN+LReLU
    conv64_k<<<NIMG * 36, 256, 0, stream>>>(pooled2, w3, conv3raw, 21);
    stats_k<float><<<6 * 64, 256, 0, stream>>>(conv3raw, P3, sums + 1536);
    finalize_k<<<2, 256, 0, stream>>>(sums + 1536, ms + 1536, g3, b3, P3);
    bnact_k<<<6285, 256, 0, stream>>>(conv3raw, ms + 1536, act3);
    // stage 4: conv4 -> stats -> BN+LReLU+normalize -> bf16 fhat
    conv64_k<<<NIMG * 36, 256, 0, stream>>>(act3, w4, conv4raw, 21);
    stats_k<float><<<6 * 64, 256, 0, stream>>>(conv4raw, P3, sums + 2304);
    finalize_k<<<2, 256, 0, stream>>>(sums + 2304, ms + 2304, g4, b4, P3);
    bnnorm_k<<<6285, 256, 0, stream>>>(conv4raw, ms + 2304, fhat);
    // similarity + top-3 + sum
    sim_k<<<NQ * NCLS * 7, 256, 0, stream>>>(fhat, out);
}

// Round 2
// 905.903 us; speedup vs baseline: 4.0275x; 4.0275x over previous
//
#include <hip/hip_runtime.h>
#include <hip/hip_bf16.h>
#include <stdint.h>

#define NQ 32
#define NCLS 5
#define SHOT 5
#define NIMG 57          // 32 query + 25 support
#define P1 7056          // 84*84
#define P2 1764          // 42*42
#define P3 441           // 21*21
#define MM (SHOT*P3)     // 2205
#define EPSB 1e-5f
#define SLOPE 0.2f

typedef __attribute__((ext_vector_type(8))) short short8;
typedef __attribute__((ext_vector_type(4))) float f32x4;

__device__ inline float ldf(const float* p) { return *p; }
__device__ inline float ldf(const __hip_bfloat16* p) { return __bfloat162float(*p); }

// ---------------- conv1: NCHW fp32 input (3ch) -> channels-last bf16 [img][p][64] ----------
__global__ __launch_bounds__(256) void conv1_k(const float* __restrict__ in1,
                                               const float* __restrict__ in2,
                                               const float* __restrict__ w,
                                               __hip_bfloat16* __restrict__ out)
{
    __shared__ float wl[27 * 65];          // [k=cin*9+tap][cout], pad 65
    int b = blockIdx.x;
    int img = b / 441;
    int r = b % 441;                       // 21x21 tiles of 4x4 pixels
    int ty = r / 21, tx = r % 21;
    int y0 = ty * 4, x0 = tx * 4;
    int lane = threadIdx.x & 63, wv = threadIdx.x >> 6;
    for (int i = threadIdx.x; i < 64 * 27; i += 256) {
        int co = i / 27, kk = i - co * 27;
        wl[kk * 65 + co] = w[i];
    }
    const float* in = (img < NQ) ? in1 + (size_t)img * 3 * P1
                                 : in2 + (size_t)(img - NQ) * 3 * P1;
    int x = x0 + wv;
    __syncthreads();
    float acc[4] = {0.f, 0.f, 0.f, 0.f};
    #pragma unroll
    for (int cin = 0; cin < 3; ++cin) {
        float v[6][3];
        #pragma unroll
        for (int ry = 0; ry < 6; ++ry) {
            int yy = y0 - 1 + ry;
            #pragma unroll
            for (int cx = 0; cx < 3; ++cx) {
                int xx = x - 1 + cx;
                bool okl = (yy >= 0) & (yy < 84) & (xx >= 0) & (xx < 84);
                v[ry][cx] = okl ? in[cin * P1 + yy * 84 + xx] : 0.f;
            }
        }
        #pragma unroll
        for (int ky = 0; ky < 3; ++ky)
            #pragma unroll
            for (int kx = 0; kx < 3; ++kx) {
                float wt = wl[(cin * 9 + ky * 3 + kx) * 65 + lane];
                #pragma unroll
                for (int i = 0; i < 4; ++i) acc[i] = fmaf(v[i + ky][kx], wt, acc[i]);
            }
    }
    #pragma unroll
    for (int i = 0; i < 4; ++i)
        out[((size_t)img * P1 + (size_t)(y0 + i) * 84 + x) * 64 + lane] = __float2bfloat16(acc[i]);
}

// ---------------- weight pack: w[co][ci][3][3] fp32 -> B-fragment-ordered bf16 ----------------
// wpk ushort index: ((t*2+half)*4 + nt)*512 + lane*8 + j
//   = bf16( w[(nt*16 + (lane&15))*576 + (half*32 + (lane>>4)*8 + j)*9 + t] )
__global__ void pack_k(const float* __restrict__ w, unsigned short* __restrict__ wpk)
{
    int i = blockIdx.x * 256 + threadIdx.x;
    if (i >= 36864) return;
    int j = i & 7, lane = (i >> 3) & 63, chunk = i >> 9;
    int nt = chunk & 3, half = (chunk >> 2) & 1, t = chunk >> 3;
    int co = nt * 16 + (lane & 15);
    int ci = half * 32 + (lane >> 4) * 8 + j;
    __hip_bfloat16 h = __float2bfloat16(w[co * 576 + ci * 9 + t]);
    wpk[i] = *reinterpret_cast<unsigned short*>(&h);
}

// ---------------- MFMA conv 64->64, channels-last bf16 in, fp32 out ----------------
// Flat-pixel M-tiling; x-border via per-lane A-frag zeroing, y-border via zero staging.
template <int S, int MBLK>
__global__ __launch_bounds__(256) void conv64m_k(const unsigned short* __restrict__ in,
                                                 const unsigned short* __restrict__ wpk,
                                                 float* __restrict__ out)
{
    constexpr int P = S * S;
    constexpr int MT = MBLK / 64;          // m-tiles per wave
    constexpr int NB = (P + MBLK - 1) / MBLK;
    constexpr int SPAN = MBLK + 2 * S + 2;
    __shared__ __align__(16) unsigned short ls[SPAN * 72];   // 72-ushort padded pixel rows
    int img = blockIdx.x / NB;
    int p0 = (blockIdx.x % NB) * MBLK;
    int tid = threadIdx.x;
    int lane = tid & 63, wv = tid >> 6;
    int col = lane & 15, quad = lane >> 4;
    const unsigned short* ib = in + (size_t)img * P * 64;
    for (int u = tid; u < SPAN * 8; u += 256) {
        int pix = u >> 3, part = u & 7;
        int p = p0 - S - 1 + pix;
        short8 v = {0, 0, 0, 0, 0, 0, 0, 0};
        if (p >= 0 && p < P) v = *(const short8*)(ib + (size_t)p * 64 + part * 8);
        *(short8*)(ls + pix * 72 + part * 8) = v;
    }
    __syncthreads();
    f32x4 acc[MT][4];
    #pragma unroll
    for (int mt = 0; mt < MT; ++mt)
        #pragma unroll
        for (int nt = 0; nt < 4; ++nt) acc[mt][nt] = (f32x4){0.f, 0.f, 0.f, 0.f};
    bool mok0[MT], mok2[MT];
    #pragma unroll
    for (int mt = 0; mt < MT; ++mt) {
        int xm = (p0 + wv * (MT * 16) + mt * 16 + col) % S;
        mok0[mt] = xm >= 1;
        mok2[mt] = xm <= S - 2;
    }
    const short8* wb = (const short8*)wpk;
    #pragma unroll
    for (int ky = 0; ky < 3; ++ky) {
        #pragma unroll
        for (int kx = 0; kx < 3; ++kx) {
            int t = ky * 3 + kx;
            int d = (ky - 1) * S + (kx - 1);
            #pragma unroll
            for (int half = 0; half < 2; ++half) {
                short8 b[4];
                #pragma unroll
                for (int nt = 0; nt < 4; ++nt)
                    b[nt] = wb[((t * 2 + half) * 4 + nt) * 64 + lane];
                #pragma unroll
                for (int mt = 0; mt < MT; ++mt) {
                    int idx = wv * (MT * 16) + mt * 16 + col + S + 1 + d;
                    short8 a = *(const short8*)(ls + idx * 72 + half * 32 + quad * 8);
                    bool ok = (kx == 0) ? mok0[mt] : (kx == 2) ? mok2[mt] : true;
                    if (!ok) a = (short8){0, 0, 0, 0, 0, 0, 0, 0};
                    #pragma unroll
                    for (int nt = 0; nt < 4; ++nt)
                        acc[mt][nt] = __builtin_amdgcn_mfma_f32_16x16x32_bf16(a, b[nt], acc[mt][nt], 0, 0, 0);
                }
            }
        }
    }
    float* ob = out + (size_t)img * P * 64;
    #pragma unroll
    for (int mt = 0; mt < MT; ++mt) {
        int tb = p0 + wv * (MT * 16) + mt * 16 + quad * 4;
        #pragma unroll
        for (int reg = 0; reg < 4; ++reg) {
            int pr = tb + reg;
            if (pr < P) {
                #pragma unroll
                for (int nt = 0; nt < 4; ++nt)
                    ob[(size_t)pr * 64 + nt * 16 + col] = acc[mt][nt][reg];
            }
        }
    }
}

// ---------------- BN stats: per (group, channel) sum / sumsq via atomics ----------------
template <typename T>
__global__ __launch_bounds__(256) void stats_k(const T* __restrict__ x, int P,
                                               float* __restrict__ sums)
{
    int g = blockIdx.x / 64;               // 64 blocks per group
    int bg = blockIdx.x % 64;
    int lane = threadIdx.x & 63, wvr = threadIdx.x >> 6;
    int img0 = (g == 0) ? 0 : NQ + (g - 1) * SHOT;
    int ni = (g == 0) ? NQ : SHOT;
    float s = 0.f, s2 = 0.f;
    for (int im = 0; im < ni; ++im) {
        const T* base = x + (size_t)(img0 + im) * P * 64;
        for (int p = bg * 4 + wvr; p < P; p += 256) {
            float v = ldf(base + (size_t)p * 64 + lane);
            s += v;
            s2 = fmaf(v, v, s2);
        }
    }
    atomicAdd(&sums[(g * 64 + lane) * 2 + 0], s);
    atomicAdd(&sums[(g * 64 + lane) * 2 + 1], s2);
}

// fold (mean, invstd, gamma, beta) -> (a, b): y = x*a + b
__global__ void finalize_k(const float* __restrict__ sums, float* __restrict__ ms,
                           const float* __restrict__ gamma, const float* __restrict__ beta, int P)
{
    int i = blockIdx.x * blockDim.x + threadIdx.x;
    if (i >= 6 * 64) return;
    int g = i >> 6, c = i & 63;
    float cnt = (float)((g == 0 ? NQ : SHOT) * P);
    float mean = sums[i * 2] / cnt;
    float var = sums[i * 2 + 1] / cnt - mean * mean;
    float a = rsqrtf(var + EPSB) * gamma[c];
    ms[i * 2] = a;
    ms[i * 2 + 1] = fmaf(-mean, a, beta[c]);
}

// ---------------- BN + LeakyReLU + 2x2 maxpool -> bf16 ----------------
template <typename T>
__global__ __launch_bounds__(256) void bnpool_k(const T* __restrict__ x, const float* __restrict__ ms,
                                                __hip_bfloat16* __restrict__ out, int Win)
{
    int Wout = Win >> 1, Pout = Wout * Wout;
    size_t idx = (size_t)blockIdx.x * 256 + threadIdx.x;
    size_t total = (size_t)NIMG * Pout * 64;
    if (idx >= total) return;
    int c = (int)(idx & 63);
    size_t t = idx >> 6;
    int p = (int)(t % Pout);
    int img = (int)(t / Pout);
    int y = p / Wout, xo = p - y * Wout;
    int g = (img < NQ) ? 0 : 1 + (img - NQ) / SHOT;
    float a = ms[(g * 64 + c) * 2], bb = ms[(g * 64 + c) * 2 + 1];
    const T* base = x + (((size_t)img * Win + 2 * y) * Win + 2 * xo) * 64 + c;
    float mx = -3.4e38f;
    #pragma unroll
    for (int dy = 0; dy < 2; ++dy)
        #pragma unroll
        for (int dx = 0; dx < 2; ++dx) {
            float v = ldf(base + ((size_t)dy * Win + dx) * 64);
            v = fmaf(v, a, bb);
            v = v >= 0.f ? v : SLOPE * v;
            mx = fmaxf(mx, v);
        }
    out[idx] = __float2bfloat16(mx);
}

// ---------------- BN + LeakyReLU (elementwise, stage 3) -> bf16 ----------------
__global__ __launch_bounds__(256) void bnact_k(const float* __restrict__ x, const float* __restrict__ ms,
                                               __hip_bfloat16* __restrict__ out)
{
    size_t idx = (size_t)blockIdx.x * 256 + threadIdx.x;
    size_t total = (size_t)NIMG * P3 * 64;
    if (idx >= total) return;
    int c = (int)(idx & 63);
    int img = (int)(idx >> 6) / P3;
    int g = (img < NQ) ? 0 : 1 + (img - NQ) / SHOT;
    float v = fmaf(x[idx], ms[(g * 64 + c) * 2], ms[(g * 64 + c) * 2 + 1]);
    out[idx] = __float2bfloat16(v >= 0.f ? v : SLOPE * v);
}

// ---------------- BN4 + LeakyReLU + per-pixel L2-normalize -> bf16 ----------------
__global__ __launch_bounds__(256) void bnnorm_k(const float* __restrict__ x, const float* __restrict__ ms,
                                                __hip_bfloat16* __restrict__ out)
{
    int lane = threadIdx.x & 63, wvr = threadIdx.x >> 6;
    int pix = blockIdx.x * 4 + wvr;        // one wave per pixel
    if (pix >= NIMG * P3) return;
    int img = pix / P3;
    int g = (img < NQ) ? 0 : 1 + (img - NQ) / SHOT;
    float v = fmaf(x[(size_t)pix * 64 + lane], ms[(g * 64 + lane) * 2], ms[(g * 64 + lane) * 2 + 1]);
    v = v >= 0.f ? v : SLOPE * v;
    float ss = v * v;
    #pragma unroll
    for (int d = 32; d > 0; d >>= 1) ss += __shfl_xor(ss, d, 64);
    out[(size_t)pix * 64 + lane] = __float2bfloat16(v * rsqrtf(ss));
}

// ---------------- similarity: MFMA bf16, per-lane running top-3, shfl merge ----------------
__device__ inline void ins3(float v, float& t0, float& t1, float& t2)
{
    if (v > t2) {
        if (v > t1) {
            t2 = t1;
            if (v > t0) { t1 = t0; t0 = v; }
            else t1 = v;
        } else t2 = v;
    }
}

__global__ __launch_bounds__(256) void sim_k(const __hip_bfloat16* __restrict__ fhat,
                                             float* __restrict__ out)
{
    __shared__ __align__(16) unsigned short sl[64 * 72];   // 64 m-rows, 72-ushort stride
    int t = blockIdx.x;
    int qb = t % 7;
    int n = (t / 7) % NCLS;
    int bq = t / (7 * NCLS);
    int lane = threadIdx.x & 63, wv = threadIdx.x >> 6;
    int col = lane & 15, quad = lane >> 4;
    int q = qb * 64 + wv * 16 + col;
    int qc = q < P3 ? q : P3 - 1;
    const unsigned short* qp = (const unsigned short*)fhat + ((size_t)bq * P3 + qc) * 64;
    short8 a0 = *(const short8*)(qp + quad * 8);
    short8 a1 = *(const short8*)(qp + 32 + quad * 8);
    const unsigned short* sp = (const unsigned short*)fhat + (size_t)(NQ + n * SHOT) * P3 * 64;
    float t0[4], t1[4], t2[4];
    #pragma unroll
    for (int i = 0; i < 4; ++i) { t0[i] = -3.4e38f; t1[i] = -3.4e38f; t2[i] = -3.4e38f; }
    for (int mc = 0; mc < 35; ++mc) {
        int m0 = mc * 64;
        __syncthreads();
        #pragma unroll
        for (int pass = 0; pass < 2; ++pass) {
            int row = (threadIdx.x >> 3) + pass * 32;
            int cc = (threadIdx.x & 7) * 8;
            int m = m0 + row;
            short8 vv = {0, 0, 0, 0, 0, 0, 0, 0};
            if (m < MM) vv = *(const short8*)(sp + (size_t)m * 64 + cc);
            *(short8*)(sl + row * 72 + cc) = vv;
        }
        __syncthreads();
        #pragma unroll
        for (int mt = 0; mt < 4; ++mt) {
            const unsigned short* sr = sl + (mt * 16 + col) * 72;
            short8 b0 = *(const short8*)(sr + quad * 8);
            short8 b1 = *(const short8*)(sr + 32 + quad * 8);
            f32x4 acc = {0.f, 0.f, 0.f, 0.f};
            acc = __builtin_amdgcn_mfma_f32_16x16x32_bf16(a0, b0, acc, 0, 0, 0);
            acc = __builtin_amdgcn_mfma_f32_16x16x32_bf16(a1, b1, acc, 0, 0, 0);
            int m = m0 + mt * 16 + col;
            if (m < MM) {
                ins3(acc[0], t0[0], t1[0], t2[0]);
                ins3(acc[1], t0[1], t1[1], t2[1]);
                ins3(acc[2], t0[2], t1[2], t2[2]);
                ins3(acc[3], t0[3], t1[3], t2[3]);
            }
        }
    }
    #pragma unroll
    for (int d = 1; d < 16; d <<= 1) {
        #pragma unroll
        for (int i = 0; i < 4; ++i) {
            float u0 = __shfl_xor(t0[i], d, 64);
            float u1 = __shfl_xor(t1[i], d, 64);
            float u2 = __shfl_xor(t2[i], d, 64);
            ins3(u0, t0[i], t1[i], t2[i]);
            ins3(u1, t0[i], t1[i], t2[i]);
            ins3(u2, t0[i], t1[i], t2[i]);
        }
    }
    if (col == 0) {
        float s = 0.f;
        int q0 = qb * 64 + wv * 16 + quad * 4;
        #pragma unroll
        for (int i = 0; i < 4; ++i)
            if (q0 + i < P3) s += t0[i] + t1[i] + t2[i];
        atomicAdd(&out[bq * NCLS + n], s);
    }
}

extern "C" void kernel_launch(void* const* d_in, const int* in_sizes, int n_in,
                              void* d_out, int out_size, void* d_ws, size_t ws_size,
                              hipStream_t stream)
{
    const float* input1 = (const float*)d_in[0];
    const float* input2 = (const float*)d_in[1];
    const float* w1 = (const float*)d_in[2];
    const float* g1 = (const float*)d_in[3];
    const float* b1 = (const float*)d_in[4];
    const float* w2 = (const float*)d_in[5];
    const float* g2 = (const float*)d_in[6];
    const float* b2 = (const float*)d_in[7];
    const float* w3 = (const float*)d_in[8];
    const float* g3 = (const float*)d_in[9];
    const float* b3 = (const float*)d_in[10];
    const float* w4 = (const float*)d_in[11];
    const float* g4 = (const float*)d_in[12];
    const float* b4 = (const float*)d_in[13];
    float* out = (float*)d_out;

    char* w8 = (char*)d_ws;
    // Region A (reused over stages): conv1raw bf16 51.5MB / conv2raw f32 25.7MB /
    //   conv3raw f32 @0, act3 bf16 @6.43MB, conv4raw f32 @9.65MB, fhat bf16 @16.1MB
    const size_t oB = 51480576;
    const size_t oT = oB + 12870144;
    __hip_bfloat16* conv1raw = (__hip_bfloat16*)(w8 + 0);
    float* conv2raw = (float*)(w8 + 0);
    float* conv3raw = (float*)(w8 + 0);
    __hip_bfloat16* act3 = (__hip_bfloat16*)(w8 + 6435072);
    float* conv4raw = (float*)(w8 + 9652608);
    __hip_bfloat16* fhat = (__hip_bfloat16*)(w8 + 16087680);
    __hip_bfloat16* pooled1 = (__hip_bfloat16*)(w8 + oB);     // 12.87MB
    __hip_bfloat16* pooled2 = (__hip_bfloat16*)(w8 + oB);     // reuse (3.2MB)
    float* sums = (float*)(w8 + oT);
    float* ms = (float*)(w8 + oT + 12288);
    unsigned short* wpk2 = (unsigned short*)(w8 + oT + 24576);
    unsigned short* wpk3 = (unsigned short*)(w8 + oT + 24576 + 73728);
    unsigned short* wpk4 = (unsigned short*)(w8 + oT + 24576 + 147456);
    if (ws_size < oT + 24576 + 221184) return;

    hipMemsetAsync(d_out, 0, (size_t)out_size * sizeof(float), stream);
    hipMemsetAsync(sums, 0, 12288, stream);

    pack_k<<<144, 256, 0, stream>>>(w2, wpk2);
    pack_k<<<144, 256, 0, stream>>>(w3, wpk3);
    pack_k<<<144, 256, 0, stream>>>(w4, wpk4);

    // stage 1: conv1 -> stats -> BN+LReLU+pool (84 -> 42)
    conv1_k<<<NIMG * 441, 256, 0, stream>>>(input1, input2, w1, conv1raw);
    stats_k<__hip_bfloat16><<<6 * 64, 256, 0, stream>>>(conv1raw, P1, sums + 0);
    finalize_k<<<2, 256, 0, stream>>>(sums + 0, ms + 0, g1, b1, P1);
    bnpool_k<__hip_bfloat16><<<25137, 256, 0, stream>>>(conv1raw, ms + 0, pooled1, 84);
    // stage 2: conv2 (MFMA) -> stats -> BN+LReLU+pool (42 -> 21)
    conv64m_k<42, 256><<<NIMG * 7, 256, 0, stream>>>((const unsigned short*)pooled1, wpk2, conv2raw);
    stats_k<float><<<6 * 64, 256, 0, stream>>>(conv2raw, P2, sums + 768);
    finalize_k<<<2, 256, 0, stream>>>(sums + 768, ms + 768, g2, b2, P2);
    bnpool_k<float><<<6285, 256, 0, stream>>>(conv2raw, ms + 768, pooled2, 42);
    // stage 3: conv3 (MFMA) -> stats -> BN+LReLU
    conv64m_k<21, 128><<<NIMG * 4, 256, 0, stream>>>((const unsigned short*)pooled2, wpk3, conv3raw);
    stats_k<float><<<6 * 64, 256, 0, stream>>>(conv3raw, P3, sums + 1536);
    finalize_k<<<2, 256, 0, stream>>>(sums + 1536, ms + 1536, g3, b3, P3);
    bnact_k<<<6285, 256, 0, stream>>>(conv3raw, ms + 1536, act3);
    // stage 4: conv4 (MFMA) -> stats -> BN+LReLU+normalize -> bf16 fhat
    conv64m_k<21, 128><<<NIMG * 4, 256, 0, stream>>>((const unsigned short*)act3, wpk4, conv4raw);
    stats_k<float><<<6 * 64, 256, 0, stream>>>(conv4raw, P3, sums + 2304);
    finalize_k<<<2, 256, 0, stream>>>(sums + 2304, ms + 2304, g4, b4, P3);
    bnnorm_k<<<6285, 256, 0, stream>>>(conv4raw, ms + 2304, fhat);
    // similarity + top-3 + sum
    sim_k<<<NQ * NCLS * 7, 256, 0, stream>>>(fhat, out);
}

// Round 3
// 631.266 us; speedup vs baseline: 5.7797x; 1.4351x over previous
//
#include <hip/hip_runtime.h>
#include <hip/hip_bf16.h>
#include <stdint.h>

#define NQ 32
#define NCLS 5
#define SHOT 5
#define NIMG 57          // 32 query + 25 support
#define P1 7056          // 84*84
#define P2 1764          // 42*42
#define P3 441           // 21*21
#define MM (SHOT*P3)     // 2205
#define EPSB 1e-5f
#define SLOPE 0.2f
#define NEGINF -3.4e38f

typedef __attribute__((ext_vector_type(8))) short short8;
typedef __attribute__((ext_vector_type(4))) float f32x4;

__device__ inline float ldf(const float* p) { return *p; }
__device__ inline float ldf(const __hip_bfloat16* p) { return __bfloat162float(*p); }

// ---------------- conv1: NCHW fp32 input (3ch) -> channels-last bf16 [img][p][64] ----------
__global__ __launch_bounds__(256) void conv1_k(const float* __restrict__ in1,
                                               const float* __restrict__ in2,
                                               const float* __restrict__ w,
                                               __hip_bfloat16* __restrict__ out)
{
    __shared__ float wl[27 * 65];          // [k=cin*9+tap][cout], pad 65
    int b = blockIdx.x;
    int img = b / 441;
    int r = b % 441;                       // 21x21 tiles of 4x4 pixels
    int ty = r / 21, tx = r % 21;
    int y0 = ty * 4, x0 = tx * 4;
    int lane = threadIdx.x & 63, wv = threadIdx.x >> 6;
    for (int i = threadIdx.x; i < 64 * 27; i += 256) {
        int co = i / 27, kk = i - co * 27;
        wl[kk * 65 + co] = w[i];
    }
    const float* in = (img < NQ) ? in1 + (size_t)img * 3 * P1
                                 : in2 + (size_t)(img - NQ) * 3 * P1;
    int x = x0 + wv;
    __syncthreads();
    float acc[4] = {0.f, 0.f, 0.f, 0.f};
    #pragma unroll
    for (int cin = 0; cin < 3; ++cin) {
        float v[6][3];
        #pragma unroll
        for (int ry = 0; ry < 6; ++ry) {
            int yy = y0 - 1 + ry;
            #pragma unroll
            for (int cx = 0; cx < 3; ++cx) {
                int xx = x - 1 + cx;
                bool okl = (yy >= 0) & (yy < 84) & (xx >= 0) & (xx < 84);
                v[ry][cx] = okl ? in[cin * P1 + yy * 84 + xx] : 0.f;
            }
        }
        #pragma unroll
        for (int ky = 0; ky < 3; ++ky)
            #pragma unroll
            for (int kx = 0; kx < 3; ++kx) {
                float wt = wl[(cin * 9 + ky * 3 + kx) * 65 + lane];
                #pragma unroll
                for (int i = 0; i < 4; ++i) acc[i] = fmaf(v[i + ky][kx], wt, acc[i]);
            }
    }
    #pragma unroll
    for (int i = 0; i < 4; ++i)
        out[((size_t)img * P1 + (size_t)(y0 + i) * 84 + x) * 64 + lane] = __float2bfloat16(acc[i]);
}

// ---------------- weight pack: w[co][ci][3][3] fp32 -> B-fragment-ordered bf16 ----------------
__global__ void pack_k(const float* __restrict__ w, unsigned short* __restrict__ wpk)
{
    int i = blockIdx.x * 256 + threadIdx.x;
    if (i >= 36864) return;
    int j = i & 7, lane = (i >> 3) & 63, chunk = i >> 9;
    int nt = chunk & 3, half = (chunk >> 2) & 1, t = chunk >> 3;
    int co = nt * 16 + (lane & 15);
    int ci = half * 32 + (lane >> 4) * 8 + j;
    __hip_bfloat16 h = __float2bfloat16(w[co * 576 + ci * 9 + t]);
    wpk[i] = *reinterpret_cast<unsigned short*>(&h);
}

// ---------------- MFMA conv 64->64, channels-last bf16 in, fp32 out ----------------
template <int S, int MBLK>
__global__ __launch_bounds__(256) void conv64m_k(const unsigned short* __restrict__ in,
                                                 const unsigned short* __restrict__ wpk,
                                                 float* __restrict__ out)
{
    constexpr int P = S * S;
    constexpr int MT = MBLK / 64;          // m-tiles per wave
    constexpr int NB = (P + MBLK - 1) / MBLK;
    constexpr int SPAN = MBLK + 2 * S + 2;
    __shared__ __align__(16) unsigned short ls[SPAN * 72];   // 72-ushort padded pixel rows
    int img = blockIdx.x / NB;
    int p0 = (blockIdx.x % NB) * MBLK;
    int tid = threadIdx.x;
    int lane = tid & 63, wv = tid >> 6;
    int col = lane & 15, quad = lane >> 4;
    const unsigned short* ib = in + (size_t)img * P * 64;
    for (int u = tid; u < SPAN * 8; u += 256) {
        int pix = u >> 3, part = u & 7;
        int p = p0 - S - 1 + pix;
        short8 v = {0, 0, 0, 0, 0, 0, 0, 0};
        if (p >= 0 && p < P) v = *(const short8*)(ib + (size_t)p * 64 + part * 8);
        *(short8*)(ls + pix * 72 + part * 8) = v;
    }
    __syncthreads();
    f32x4 acc[MT][4];
    #pragma unroll
    for (int mt = 0; mt < MT; ++mt)
        #pragma unroll
        for (int nt = 0; nt < 4; ++nt) acc[mt][nt] = (f32x4){0.f, 0.f, 0.f, 0.f};
    bool mok0[MT], mok2[MT];
    #pragma unroll
    for (int mt = 0; mt < MT; ++mt) {
        int xm = (p0 + wv * (MT * 16) + mt * 16 + col) % S;
        mok0[mt] = xm >= 1;
        mok2[mt] = xm <= S - 2;
    }
    const short8* wb = (const short8*)wpk;
    #pragma unroll
    for (int ky = 0; ky < 3; ++ky) {
        #pragma unroll
        for (int kx = 0; kx < 3; ++kx) {
            int t = ky * 3 + kx;
            int d = (ky - 1) * S + (kx - 1);
            #pragma unroll
            for (int half = 0; half < 2; ++half) {
                short8 b[4];
                #pragma unroll
                for (int nt = 0; nt < 4; ++nt)
                    b[nt] = wb[((t * 2 + half) * 4 + nt) * 64 + lane];
                #pragma unroll
                for (int mt = 0; mt < MT; ++mt) {
                    int idx = wv * (MT * 16) + mt * 16 + col + S + 1 + d;
                    short8 a = *(const short8*)(ls + idx * 72 + half * 32 + quad * 8);
                    bool ok = (kx == 0) ? mok0[mt] : (kx == 2) ? mok2[mt] : true;
                    if (!ok) a = (short8){0, 0, 0, 0, 0, 0, 0, 0};
                    #pragma unroll
                    for (int nt = 0; nt < 4; ++nt)
                        acc[mt][nt] = __builtin_amdgcn_mfma_f32_16x16x32_bf16(a, b[nt], acc[mt][nt], 0, 0, 0);
                }
            }
        }
    }
    float* ob = out + (size_t)img * P * 64;
    #pragma unroll
    for (int mt = 0; mt < MT; ++mt) {
        int tb = p0 + wv * (MT * 16) + mt * 16 + quad * 4;
        #pragma unroll
        for (int reg = 0; reg < 4; ++reg) {
            int pr = tb + reg;
            if (pr < P) {
                #pragma unroll
                for (int nt = 0; nt < 4; ++nt)
                    ob[(size_t)pr * 64 + nt * 16 + col] = acc[mt][nt][reg];
            }
        }
    }
}

// ---------------- BN stats: per (group, channel) sum / sumsq, LDS pre-reduce + atomics ----------------
template <typename T>
__global__ __launch_bounds__(256) void stats_k(const T* __restrict__ x, int P,
                                               float* __restrict__ sums)
{
    __shared__ float red[2][4][64];
    int g = blockIdx.x / 64;               // 64 blocks per group
    int bg = blockIdx.x % 64;
    int lane = threadIdx.x & 63, wvr = threadIdx.x >> 6;
    int img0 = (g == 0) ? 0 : NQ + (g - 1) * SHOT;
    int ni = (g == 0) ? NQ : SHOT;
    float s = 0.f, s2 = 0.f;
    for (int im = 0; im < ni; ++im) {
        const T* base = x + (size_t)(img0 + im) * P * 64;
        for (int p = bg * 4 + wvr; p < P; p += 256) {
            float v = ldf(base + (size_t)p * 64 + lane);
            s += v;
            s2 = fmaf(v, v, s2);
        }
    }
    red[0][wvr][lane] = s;
    red[1][wvr][lane] = s2;
    __syncthreads();
    if (wvr == 0) {
        s = red[0][0][lane] + red[0][1][lane] + red[0][2][lane] + red[0][3][lane];
        s2 = red[1][0][lane] + red[1][1][lane] + red[1][2][lane] + red[1][3][lane];
        atomicAdd(&sums[(g * 64 + lane) * 2 + 0], s);
        atomicAdd(&sums[(g * 64 + lane) * 2 + 1], s2);
    }
}

// fold (mean, invstd, gamma, beta) -> (a, b): y = x*a + b
__global__ void finalize_k(const float* __restrict__ sums, float* __restrict__ ms,
                           const float* __restrict__ gamma, const float* __restrict__ beta, int P)
{
    int i = blockIdx.x * blockDim.x + threadIdx.x;
    if (i >= 6 * 64) return;
    int g = i >> 6, c = i & 63;
    float cnt = (float)((g == 0 ? NQ : SHOT) * P);
    float mean = sums[i * 2] / cnt;
    float var = sums[i * 2 + 1] / cnt - mean * mean;
    float a = rsqrtf(var + EPSB) * gamma[c];
    ms[i * 2] = a;
    ms[i * 2 + 1] = fmaf(-mean, a, beta[c]);
}

// ---------------- BN + LeakyReLU + 2x2 maxpool -> bf16 ----------------
template <typename T>
__global__ __launch_bounds__(256) void bnpool_k(const T* __restrict__ x, const float* __restrict__ ms,
                                                __hip_bfloat16* __restrict__ out, int Win)
{
    int Wout = Win >> 1, Pout = Wout * Wout;
    size_t idx = (size_t)blockIdx.x * 256 + threadIdx.x;
    size_t total = (size_t)NIMG * Pout * 64;
    if (idx >= total) return;
    int c = (int)(idx & 63);
    size_t t = idx >> 6;
    int p = (int)(t % Pout);
    int img = (int)(t / Pout);
    int y = p / Wout, xo = p - y * Wout;
    int g = (img < NQ) ? 0 : 1 + (img - NQ) / SHOT;
    float a = ms[(g * 64 + c) * 2], bb = ms[(g * 64 + c) * 2 + 1];
    const T* base = x + (((size_t)img * Win + 2 * y) * Win + 2 * xo) * 64 + c;
    float mx = -3.4e38f;
    #pragma unroll
    for (int dy = 0; dy < 2; ++dy)
        #pragma unroll
        for (int dx = 0; dx < 2; ++dx) {
            float v = ldf(base + ((size_t)dy * Win + dx) * 64);
            v = fmaf(v, a, bb);
            v = v >= 0.f ? v : SLOPE * v;
            mx = fmaxf(mx, v);
        }
    out[idx] = __float2bfloat16(mx);
}

// ---------------- BN + LeakyReLU (elementwise, stage 3) -> bf16 ----------------
__global__ __launch_bounds__(256) void bnact_k(const float* __restrict__ x, const float* __restrict__ ms,
                                               __hip_bfloat16* __restrict__ out)
{
    size_t idx = (size_t)blockIdx.x * 256 + threadIdx.x;
    size_t total = (size_t)NIMG * P3 * 64;
    if (idx >= total) return;
    int c = (int)(idx & 63);
    int img = (int)(idx >> 6) / P3;
    int g = (img < NQ) ? 0 : 1 + (img - NQ) / SHOT;
    float v = fmaf(x[idx], ms[(g * 64 + c) * 2], ms[(g * 64 + c) * 2 + 1]);
    out[idx] = __float2bfloat16(v >= 0.f ? v : SLOPE * v);
}

// ---------------- BN4 + LeakyReLU + per-pixel L2-normalize -> bf16 ----------------
__global__ __launch_bounds__(256) void bnnorm_k(const float* __restrict__ x, const float* __restrict__ ms,
                                                __hip_bfloat16* __restrict__ out)
{
    int lane = threadIdx.x & 63, wvr = threadIdx.x >> 6;
    int pix = blockIdx.x * 4 + wvr;        // one wave per pixel
    if (pix >= NIMG * P3) return;
    int img = pix / P3;
    int g = (img < NQ) ? 0 : 1 + (img - NQ) / SHOT;
    float v = fmaf(x[(size_t)pix * 64 + lane], ms[(g * 64 + lane) * 2], ms[(g * 64 + lane) * 2 + 1]);
    v = v >= 0.f ? v : SLOPE * v;
    float ss = v * v;
    #pragma unroll
    for (int d = 32; d > 0; d >>= 1) ss += __shfl_xor(ss, d, 64);
    out[(size_t)pix * 64 + lane] = __float2bfloat16(v * rsqrtf(ss));
}

// ---------------- similarity: MFMA bf16, branchless per-lane top-3, shfl merge ----------------
// Branchless sorted insert (invariant t0 >= t1 >= t2):
//   t1' = med3(v, t0, t1); t2' = med3(v, t1, t2); t0' = max(t0, v)
__device__ __forceinline__ void ins3(float v, float& t0, float& t1, float& t2)
{
    float n1 = __builtin_amdgcn_fmed3f(v, t0, t1);
    float n2 = __builtin_amdgcn_fmed3f(v, t1, t2);
    t0 = fmaxf(t0, v);
    t1 = n1;
    t2 = n2;
}

__global__ __launch_bounds__(256) void sim_k(const __hip_bfloat16* __restrict__ fhat,
                                             float* __restrict__ out)
{
    __shared__ __align__(16) unsigned short sl[64 * 72];   // 64 m-rows, 72-ushort stride
    int t = blockIdx.x;
    int qb = t % 7;
    int n = (t / 7) % NCLS;
    int bq = t / (7 * NCLS);
    int lane = threadIdx.x & 63, wv = threadIdx.x >> 6;
    int col = lane & 15, quad = lane >> 4;
    int q = qb * 64 + wv * 16 + col;
    int qc = q < P3 ? q : P3 - 1;
    const unsigned short* qp = (const unsigned short*)fhat + ((size_t)bq * P3 + qc) * 64;
    short8 a0 = *(const short8*)(qp + quad * 8);
    short8 a1 = *(const short8*)(qp + 32 + quad * 8);
    const unsigned short* sp = (const unsigned short*)fhat + (size_t)(NQ + n * SHOT) * P3 * 64;
    float t0[4], t1[4], t2[4];
    #pragma unroll
    for (int i = 0; i < 4; ++i) { t0[i] = NEGINF; t1[i] = NEGINF; t2[i] = NEGINF; }
    for (int mc = 0; mc < 35; ++mc) {
        int m0 = mc * 64;
        __syncthreads();
        #pragma unroll
        for (int pass = 0; pass < 2; ++pass) {
            int row = (threadIdx.x >> 3) + pass * 32;
            int cc = (threadIdx.x & 7) * 8;
            int m = m0 + row;
            short8 vv = {0, 0, 0, 0, 0, 0, 0, 0};
            if (m < MM) vv = *(const short8*)(sp + (size_t)m * 64 + cc);
            *(short8*)(sl + row * 72 + cc) = vv;
        }
        __syncthreads();
        #pragma unroll
        for (int mt = 0; mt < 4; ++mt) {
            const unsigned short* sr = sl + (mt * 16 + col) * 72;
            short8 b0 = *(const short8*)(sr + quad * 8);
            short8 b1 = *(const short8*)(sr + 32 + quad * 8);
            f32x4 acc = {0.f, 0.f, 0.f, 0.f};
            acc = __builtin_amdgcn_mfma_f32_16x16x32_bf16(a0, b0, acc, 0, 0, 0);
            acc = __builtin_amdgcn_mfma_f32_16x16x32_bf16(a1, b1, acc, 0, 0, 0);
            // wave-uniform guard: only the last m-chunk has OOB columns
            if (m0 + mt * 16 + 15 < MM) {
                #pragma unroll
                for (int i = 0; i < 4; ++i) ins3(acc[i], t0[i], t1[i], t2[i]);
            } else {
                float bias = (m0 + mt * 16 + col < MM) ? 0.f : NEGINF;
                #pragma unroll
                for (int i = 0; i < 4; ++i) ins3(acc[i] + bias, t0[i], t1[i], t2[i]);
            }
        }
    }
    #pragma unroll
    for (int d = 1; d < 16; d <<= 1) {
        #pragma unroll
        for (int i = 0; i < 4; ++i) {
            float u0 = __shfl_xor(t0[i], d, 64);
            float u1 = __shfl_xor(t1[i], d, 64);
            float u2 = __shfl_xor(t2[i], d, 64);
            ins3(u0, t0[i], t1[i], t2[i]);
            ins3(u1, t0[i], t1[i], t2[i]);
            ins3(u2, t0[i], t1[i], t2[i]);
        }
    }
    if (col == 0) {
        float s = 0.f;
        int q0 = qb * 64 + wv * 16 + quad * 4;
        #pragma unroll
        for (int i = 0; i < 4; ++i)
            if (q0 + i < P3) s += t0[i] + t1[i] + t2[i];
        atomicAdd(&out[bq * NCLS + n], s);
    }
}

extern "C" void kernel_launch(void* const* d_in, const int* in_sizes, int n_in,
                              void* d_out, int out_size, void* d_ws, size_t ws_size,
                              hipStream_t stream)
{
    const float* input1 = (const float*)d_in[0];
    const float* input2 = (const float*)d_in[1];
    const float* w1 = (const float*)d_in[2];
    const float* g1 = (const float*)d_in[3];
    const float* b1 = (const float*)d_in[4];
    const float* w2 = (const float*)d_in[5];
    const float* g2 = (const float*)d_in[6];
    const float* b2 = (const float*)d_in[7];
    const float* w3 = (const float*)d_in[8];
    const float* g3 = (const float*)d_in[9];
    const float* b3 = (const float*)d_in[10];
    const float* w4 = (const float*)d_in[11];
    const float* g4 = (const float*)d_in[12];
    const float* b4 = (const float*)d_in[13];
    float* out = (float*)d_out;

    char* w8 = (char*)d_ws;
    const size_t oB = 51480576;
    const size_t oT = oB + 12870144;
    __hip_bfloat16* conv1raw = (__hip_bfloat16*)(w8 + 0);
    float* conv2raw = (float*)(w8 + 0);
    float* conv3raw = (float*)(w8 + 0);
    __hip_bfloat16* act3 = (__hip_bfloat16*)(w8 + 6435072);
    float* conv4raw = (float*)(w8 + 9652608);
    __hip_bfloat16* fhat = (__hip_bfloat16*)(w8 + 16087680);
    __hip_bfloat16* pooled1 = (__hip_bfloat16*)(w8 + oB);     // 12.87MB
    __hip_bfloat16* pooled2 = (__hip_bfloat16*)(w8 + oB);     // reuse (3.2MB)
    float* sums = (float*)(w8 + oT);
    float* ms = (float*)(w8 + oT + 12288);
    unsigned short* wpk2 = (unsigned short*)(w8 + oT + 24576);
    unsigned short* wpk3 = (unsigned short*)(w8 + oT + 24576 + 73728);
    unsigned short* wpk4 = (unsigned short*)(w8 + oT + 24576 + 147456);
    if (ws_size < oT + 24576 + 221184) return;

    hipMemsetAsync(d_out, 0, (size_t)out_size * sizeof(float), stream);
    hipMemsetAsync(sums, 0, 12288, stream);

    pack_k<<<144, 256, 0, stream>>>(w2, wpk2);
    pack_k<<<144, 256, 0, stream>>>(w3, wpk3);
    pack_k<<<144, 256, 0, stream>>>(w4, wpk4);

    // stage 1: conv1 -> stats -> BN+LReLU+pool (84 -> 42)
    conv1_k<<<NIMG * 441, 256, 0, stream>>>(input1, input2, w1, conv1raw);
    stats_k<__hip_bfloat16><<<6 * 64, 256, 0, stream>>>(conv1raw, P1, sums + 0);
    finalize_k<<<2, 256, 0, stream>>>(sums + 0, ms + 0, g1, b1, P1);
    bnpool_k<__hip_bfloat16><<<25137, 256, 0, stream>>>(conv1raw, ms + 0, pooled1, 84);
    // stage 2: conv2 (MFMA) -> stats -> BN+LReLU+pool (42 -> 21)
    conv64m_k<42, 256><<<NIMG * 7, 256, 0, stream>>>((const unsigned short*)pooled1, wpk2, conv2raw);
    stats_k<float><<<6 * 64, 256, 0, stream>>>(conv2raw, P2, sums + 768);
    finalize_k<<<2, 256, 0, stream>>>(sums + 768, ms + 768, g2, b2, P2);
    bnpool_k<float><<<6285, 256, 0, stream>>>(conv2raw, ms + 768, pooled2, 42);
    // stage 3: conv3 (MFMA) -> stats -> BN+LReLU
    conv64m_k<21, 128><<<NIMG * 4, 256, 0, stream>>>((const unsigned short*)pooled2, wpk3, conv3raw);
    stats_k<float><<<6 * 64, 256, 0, stream>>>(conv3raw, P3, sums + 1536);
    finalize_k<<<2, 256, 0, stream>>>(sums + 1536, ms + 1536, g3, b3, P3);
    bnact_k<<<6285, 256, 0, stream>>>(conv3raw, ms + 1536, act3);
    // stage 4: conv4 (MFMA) -> stats -> BN+LReLU+normalize -> bf16 fhat
    conv64m_k<21, 128><<<NIMG * 4, 256, 0, stream>>>((const unsigned short*)act3, wpk4, conv4raw);
    stats_k<float><<<6 * 64, 256, 0, stream>>>(conv4raw, P3, sums + 2304);
    finalize_k<<<2, 256, 0, stream>>>(sums + 2304, ms + 2304, g4, b4, P3);
    bnnorm_k<<<6285, 256, 0, stream>>>(conv4raw, ms + 2304, fhat);
    // similarity + top-3 + sum
    sim_k<<<NQ * NCLS * 7, 256, 0, stream>>>(fhat, out);
}

// Round 4
// 509.138 us; speedup vs baseline: 7.1661x; 1.2399x over previous
//
#include <hip/hip_runtime.h>
#include <hip/hip_bf16.h>
#include <stdint.h>

#define NQ 32
#define NCLS 5
#define SHOT 5
#define NIMG 57          // 32 query + 25 support
#define P1 7056          // 84*84
#define P2 1764          // 42*42
#define P3 441           // 21*21
#define MM (SHOT*P3)     // 2205
#define EPSB 1e-5f
#define SLOPE 0.2f
#define NEGINF -3.4e38f
#define NREP 32          // stats atomic replication factor

typedef __attribute__((ext_vector_type(8))) short short8;
typedef __attribute__((ext_vector_type(4))) float f32x4;

__device__ inline float ldf(const float* p) { return *p; }
__device__ inline float ldf(const __hip_bfloat16* p) { return __bfloat162float(*p); }

// ---------------- conv1: NCHW fp32 input (3ch) -> channels-last bf16, fused BN stats ----------
__global__ __launch_bounds__(256) void conv1_k(const float* __restrict__ in1,
                                               const float* __restrict__ in2,
                                               const float* __restrict__ w,
                                               __hip_bfloat16* __restrict__ out,
                                               float* __restrict__ sums)
{
    __shared__ float wl[27 * 65];          // [k=cin*9+tap][cout], pad 65
    __shared__ float rs[4][64], rs2[4][64];
    int b = blockIdx.x;
    int img = b / 441;
    int r = b % 441;                       // 21x21 tiles of 4x4 pixels
    int ty = r / 21, tx = r % 21;
    int y0 = ty * 4, x0 = tx * 4;
    int lane = threadIdx.x & 63, wv = threadIdx.x >> 6;
    for (int i = threadIdx.x; i < 64 * 27; i += 256) {
        int co = i / 27, kk = i - co * 27;
        wl[kk * 65 + co] = w[i];
    }
    const float* in = (img < NQ) ? in1 + (size_t)img * 3 * P1
                                 : in2 + (size_t)(img - NQ) * 3 * P1;
    int x = x0 + wv;
    __syncthreads();
    float acc[4] = {0.f, 0.f, 0.f, 0.f};
    #pragma unroll
    for (int cin = 0; cin < 3; ++cin) {
        float v[6][3];
        #pragma unroll
        for (int ry = 0; ry < 6; ++ry) {
            int yy = y0 - 1 + ry;
            #pragma unroll
            for (int cx = 0; cx < 3; ++cx) {
                int xx = x - 1 + cx;
                bool okl = (yy >= 0) & (yy < 84) & (xx >= 0) & (xx < 84);
                v[ry][cx] = okl ? in[cin * P1 + yy * 84 + xx] : 0.f;
            }
        }
        #pragma unroll
        for (int ky = 0; ky < 3; ++ky)
            #pragma unroll
            for (int kx = 0; kx < 3; ++kx) {
                float wt = wl[(cin * 9 + ky * 3 + kx) * 65 + lane];
                #pragma unroll
                for (int i = 0; i < 4; ++i) acc[i] = fmaf(v[i + ky][kx], wt, acc[i]);
            }
    }
    float s = 0.f, s2 = 0.f;
    #pragma unroll
    for (int i = 0; i < 4; ++i) {
        out[((size_t)img * P1 + (size_t)(y0 + i) * 84 + x) * 64 + lane] = __float2bfloat16(acc[i]);
        s += acc[i];
        s2 = fmaf(acc[i], acc[i], s2);
    }
    rs[wv][lane] = s;
    rs2[wv][lane] = s2;
    __syncthreads();
    if (wv == 0) {
        int g = (img < NQ) ? 0 : 1 + (img - NQ) / SHOT;
        int rep = blockIdx.x & (NREP - 1);
        float ts = rs[0][lane] + rs[1][lane] + rs[2][lane] + rs[3][lane];
        float ts2 = rs2[0][lane] + rs2[1][lane] + rs2[2][lane] + rs2[3][lane];
        float* base = sums + ((size_t)(g * 64 + lane) * 2) * NREP + rep;
        atomicAdd(base, ts);
        atomicAdd(base + NREP, ts2);
    }
}

// ---------------- weight pack: w[co][ci][3][3] fp32 -> B-fragment-ordered bf16 ----------------
__global__ void pack_k(const float* __restrict__ w, unsigned short* __restrict__ wpk)
{
    int i = blockIdx.x * 256 + threadIdx.x;
    if (i >= 36864) return;
    int j = i & 7, lane = (i >> 3) & 63, chunk = i >> 9;
    int nt = chunk & 3, half = (chunk >> 2) & 1, t = chunk >> 3;
    int co = nt * 16 + (lane & 15);
    int ci = half * 32 + (lane >> 4) * 8 + j;
    __hip_bfloat16 h = __float2bfloat16(w[co * 576 + ci * 9 + t]);
    wpk[i] = *reinterpret_cast<unsigned short*>(&h);
}

// ---------------- MFMA conv 64->64, channels-last bf16 in, fp32 out, fused BN stats ----------
template <int S, int MBLK>
__global__ __launch_bounds__(256) void conv64m_k(const unsigned short* __restrict__ in,
                                                 const unsigned short* __restrict__ wpk,
                                                 float* __restrict__ out,
                                                 float* __restrict__ sums)
{
    constexpr int P = S * S;
    constexpr int MT = MBLK / 64;          // m-tiles per wave
    constexpr int NB = (P + MBLK - 1) / MBLK;
    constexpr int SPAN = MBLK + 2 * S + 2;
    __shared__ __align__(16) unsigned short ls[SPAN * 72];   // 72-ushort padded pixel rows
    __shared__ float qs[4][64], qs2[4][64];
    int img = blockIdx.x / NB;
    int p0 = (blockIdx.x % NB) * MBLK;
    int tid = threadIdx.x;
    int lane = tid & 63, wv = tid >> 6;
    int col = lane & 15, quad = lane >> 4;
    const unsigned short* ib = in + (size_t)img * P * 64;
    for (int u = tid; u < SPAN * 8; u += 256) {
        int pix = u >> 3, part = u & 7;
        int p = p0 - S - 1 + pix;
        short8 v = {0, 0, 0, 0, 0, 0, 0, 0};
        if (p >= 0 && p < P) v = *(const short8*)(ib + (size_t)p * 64 + part * 8);
        *(short8*)(ls + pix * 72 + part * 8) = v;
    }
    __syncthreads();
    f32x4 acc[MT][4];
    #pragma unroll
    for (int mt = 0; mt < MT; ++mt)
        #pragma unroll
        for (int nt = 0; nt < 4; ++nt) acc[mt][nt] = (f32x4){0.f, 0.f, 0.f, 0.f};
    bool mok0[MT], mok2[MT];
    #pragma unroll
    for (int mt = 0; mt < MT; ++mt) {
        int xm = (p0 + wv * (MT * 16) + mt * 16 + col) % S;
        mok0[mt] = xm >= 1;
        mok2[mt] = xm <= S - 2;
    }
    const short8* wb = (const short8*)wpk;
    #pragma unroll
    for (int ky = 0; ky < 3; ++ky) {
        #pragma unroll
        for (int kx = 0; kx < 3; ++kx) {
            int t = ky * 3 + kx;
            int d = (ky - 1) * S + (kx - 1);
            #pragma unroll
            for (int half = 0; half < 2; ++half) {
                short8 b[4];
                #pragma unroll
                for (int nt = 0; nt < 4; ++nt)
                    b[nt] = wb[((t * 2 + half) * 4 + nt) * 64 + lane];
                #pragma unroll
                for (int mt = 0; mt < MT; ++mt) {
                    int idx = wv * (MT * 16) + mt * 16 + col + S + 1 + d;
                    short8 a = *(const short8*)(ls + idx * 72 + half * 32 + quad * 8);
                    bool ok = (kx == 0) ? mok0[mt] : (kx == 2) ? mok2[mt] : true;
                    if (!ok) a = (short8){0, 0, 0, 0, 0, 0, 0, 0};
                    #pragma unroll
                    for (int nt = 0; nt < 4; ++nt)
                        acc[mt][nt] = __builtin_amdgcn_mfma_f32_16x16x32_bf16(a, b[nt], acc[mt][nt], 0, 0, 0);
                }
            }
        }
    }
    float s[4] = {0.f, 0.f, 0.f, 0.f}, s2[4] = {0.f, 0.f, 0.f, 0.f};
    float* ob = out + (size_t)img * P * 64;
    #pragma unroll
    for (int mt = 0; mt < MT; ++mt) {
        int tb = p0 + wv * (MT * 16) + mt * 16 + quad * 4;
        #pragma unroll
        for (int reg = 0; reg < 4; ++reg) {
            int pr = tb + reg;
            if (pr < P) {
                #pragma unroll
                for (int nt = 0; nt < 4; ++nt) {
                    float v = acc[mt][nt][reg];
                    ob[(size_t)pr * 64 + nt * 16 + col] = v;
                    s[nt] += v;
                    s2[nt] = fmaf(v, v, s2[nt]);
                }
            }
        }
    }
    // reduce over quad lanes (same channel nt*16+col)
    #pragma unroll
    for (int d = 16; d < 64; d <<= 1)
        #pragma unroll
        for (int nt = 0; nt < 4; ++nt) {
            s[nt] += __shfl_xor(s[nt], d, 64);
            s2[nt] += __shfl_xor(s2[nt], d, 64);
        }
    if (quad == 0) {
        #pragma unroll
        for (int nt = 0; nt < 4; ++nt) {
            qs[wv][nt * 16 + col] = s[nt];
            qs2[wv][nt * 16 + col] = s2[nt];
        }
    }
    __syncthreads();
    if (wv == 0) {
        int g = (img < NQ) ? 0 : 1 + (img - NQ) / SHOT;
        int rep = blockIdx.x & (NREP - 1);
        float ts = qs[0][lane] + qs[1][lane] + qs[2][lane] + qs[3][lane];
        float ts2 = qs2[0][lane] + qs2[1][lane] + qs2[2][lane] + qs2[3][lane];
        float* base = sums + ((size_t)(g * 64 + lane) * 2) * NREP + rep;
        atomicAdd(base, ts);
        atomicAdd(base + NREP, ts2);
    }
}

// fold (mean, invstd, gamma, beta) -> (a, b): y = x*a + b   (sums has NREP replicas)
__global__ void finalize_k(const float* __restrict__ sums, float* __restrict__ ms,
                           const float* __restrict__ gamma, const float* __restrict__ beta, int P)
{
    int i = blockIdx.x * blockDim.x + threadIdx.x;
    if (i >= 6 * 64) return;
    int g = i >> 6, c = i & 63;
    const float* ps = sums + (size_t)i * 2 * NREP;
    float s = 0.f, s2 = 0.f;
    #pragma unroll
    for (int r = 0; r < NREP; ++r) { s += ps[r]; s2 += ps[NREP + r]; }
    float cnt = (float)((g == 0 ? NQ : SHOT) * P);
    float mean = s / cnt;
    float var = s2 / cnt - mean * mean;
    float a = rsqrtf(var + EPSB) * gamma[c];
    ms[i * 2] = a;
    ms[i * 2 + 1] = fmaf(-mean, a, beta[c]);
}

// ---------------- BN + LeakyReLU + 2x2 maxpool -> bf16 ----------------
template <typename T>
__global__ __launch_bounds__(256) void bnpool_k(const T* __restrict__ x, const float* __restrict__ ms,
                                                __hip_bfloat16* __restrict__ out, int Win)
{
    int Wout = Win >> 1, Pout = Wout * Wout;
    size_t idx = (size_t)blockIdx.x * 256 + threadIdx.x;
    size_t total = (size_t)NIMG * Pout * 64;
    if (idx >= total) return;
    int c = (int)(idx & 63);
    size_t t = idx >> 6;
    int p = (int)(t % Pout);
    int img = (int)(t / Pout);
    int y = p / Wout, xo = p - y * Wout;
    int g = (img < NQ) ? 0 : 1 + (img - NQ) / SHOT;
    float a = ms[(g * 64 + c) * 2], bb = ms[(g * 64 + c) * 2 + 1];
    const T* base = x + (((size_t)img * Win + 2 * y) * Win + 2 * xo) * 64 + c;
    float mx = -3.4e38f;
    #pragma unroll
    for (int dy = 0; dy < 2; ++dy)
        #pragma unroll
        for (int dx = 0; dx < 2; ++dx) {
            float v = ldf(base + ((size_t)dy * Win + dx) * 64);
            v = fmaf(v, a, bb);
            v = v >= 0.f ? v : SLOPE * v;
            mx = fmaxf(mx, v);
        }
    out[idx] = __float2bfloat16(mx);
}

// ---------------- BN + LeakyReLU (elementwise, stage 3) -> bf16 ----------------
__global__ __launch_bounds__(256) void bnact_k(const float* __restrict__ x, const float* __restrict__ ms,
                                               __hip_bfloat16* __restrict__ out)
{
    size_t idx = (size_t)blockIdx.x * 256 + threadIdx.x;
    size_t total = (size_t)NIMG * P3 * 64;
    if (idx >= total) return;
    int c = (int)(idx & 63);
    int img = (int)(idx >> 6) / P3;
    int g = (img < NQ) ? 0 : 1 + (img - NQ) / SHOT;
    float v = fmaf(x[idx], ms[(g * 64 + c) * 2], ms[(g * 64 + c) * 2 + 1]);
    out[idx] = __float2bfloat16(v >= 0.f ? v : SLOPE * v);
}

// ---------------- BN4 + LeakyReLU + per-pixel L2-normalize -> bf16 ----------------
__global__ __launch_bounds__(256) void bnnorm_k(const float* __restrict__ x, const float* __restrict__ ms,
                                                __hip_bfloat16* __restrict__ out)
{
    int lane = threadIdx.x & 63, wvr = threadIdx.x >> 6;
    int pix = blockIdx.x * 4 + wvr;        // one wave per pixel
    if (pix >= NIMG * P3) return;
    int img = pix / P3;
    int g = (img < NQ) ? 0 : 1 + (img - NQ) / SHOT;
    float v = fmaf(x[(size_t)pix * 64 + lane], ms[(g * 64 + lane) * 2], ms[(g * 64 + lane) * 2 + 1]);
    v = v >= 0.f ? v : SLOPE * v;
    float ss = v * v;
    #pragma unroll
    for (int d = 32; d > 0; d >>= 1) ss += __shfl_xor(ss, d, 64);
    out[(size_t)pix * 64 + lane] = __float2bfloat16(v * rsqrtf(ss));
}

// ---------------- similarity: MFMA bf16, branchless per-lane top-3, shfl merge ----------------
__device__ __forceinline__ void ins3(float v, float& t0, float& t1, float& t2)
{
    float n1 = __builtin_amdgcn_fmed3f(v, t0, t1);
    float n2 = __builtin_amdgcn_fmed3f(v, t1, t2);
    t0 = fmaxf(t0, v);
    t1 = n1;
    t2 = n2;
}

__global__ __launch_bounds__(256) void sim_k(const __hip_bfloat16* __restrict__ fhat,
                                             float* __restrict__ out)
{
    __shared__ __align__(16) unsigned short sl[64 * 72];   // 64 m-rows, 72-ushort stride
    int t = blockIdx.x;
    int qb = t % 7;
    int n = (t / 7) % NCLS;
    int bq = t / (7 * NCLS);
    int lane = threadIdx.x & 63, wv = threadIdx.x >> 6;
    int col = lane & 15, quad = lane >> 4;
    int q = qb * 64 + wv * 16 + col;
    int qc = q < P3 ? q : P3 - 1;
    const unsigned short* qp = (const unsigned short*)fhat + ((size_t)bq * P3 + qc) * 64;
    short8 a0 = *(const short8*)(qp + quad * 8);
    short8 a1 = *(const short8*)(qp + 32 + quad * 8);
    const unsigned short* sp = (const unsigned short*)fhat + (size_t)(NQ + n * SHOT) * P3 * 64;
    float t0[4], t1[4], t2[4];
    #pragma unroll
    for (int i = 0; i < 4; ++i) { t0[i] = NEGINF; t1[i] = NEGINF; t2[i] = NEGINF; }
    for (int mc = 0; mc < 35; ++mc) {
        int m0 = mc * 64;
        __syncthreads();
        #pragma unroll
        for (int pass = 0; pass < 2; ++pass) {
            int row = (threadIdx.x >> 3) + pass * 32;
            int cc = (threadIdx.x & 7) * 8;
            int m = m0 + row;
            short8 vv = {0, 0, 0, 0, 0, 0, 0, 0};
            if (m < MM) vv = *(const short8*)(sp + (size_t)m * 64 + cc);
            *(short8*)(sl + row * 72 + cc) = vv;
        }
        __syncthreads();
        #pragma unroll
        for (int mt = 0; mt < 4; ++mt) {
            const unsigned short* sr = sl + (mt * 16 + col) * 72;
            short8 b0 = *(const short8*)(sr + quad * 8);
            short8 b1 = *(const short8*)(sr + 32 + quad * 8);
            f32x4 acc = {0.f, 0.f, 0.f, 0.f};
            acc = __builtin_amdgcn_mfma_f32_16x16x32_bf16(a0, b0, acc, 0, 0, 0);
            acc = __builtin_amdgcn_mfma_f32_16x16x32_bf16(a1, b1, acc, 0, 0, 0);
            if (m0 + mt * 16 + 15 < MM) {
                #pragma unroll
                for (int i = 0; i < 4; ++i) ins3(acc[i], t0[i], t1[i], t2[i]);
            } else {
                float bias = (m0 + mt * 16 + col < MM) ? 0.f : NEGINF;
                #pragma unroll
                for (int i = 0; i < 4; ++i) ins3(acc[i] + bias, t0[i], t1[i], t2[i]);
            }
        }
    }
    #pragma unroll
    for (int d = 1; d < 16; d <<= 1) {
        #pragma unroll
        for (int i = 0; i < 4; ++i) {
            float u0 = __shfl_xor(t0[i], d, 64);
            float u1 = __shfl_xor(t1[i], d, 64);
            float u2 = __shfl_xor(t2[i], d, 64);
            ins3(u0, t0[i], t1[i], t2[i]);
            ins3(u1, t0[i], t1[i], t2[i]);
            ins3(u2, t0[i], t1[i], t2[i]);
        }
    }
    if (col == 0) {
        float s = 0.f;
        int q0 = qb * 64 + wv * 16 + quad * 4;
        #pragma unroll
        for (int i = 0; i < 4; ++i)
            if (q0 + i < P3) s += t0[i] + t1[i] + t2[i];
        atomicAdd(&out[bq * NCLS + n], s);
    }
}

extern "C" void kernel_launch(void* const* d_in, const int* in_sizes, int n_in,
                              void* d_out, int out_size, void* d_ws, size_t ws_size,
                              hipStream_t stream)
{
    const float* input1 = (const float*)d_in[0];
    const float* input2 = (const float*)d_in[1];
    const float* w1 = (const float*)d_in[2];
    const float* g1 = (const float*)d_in[3];
    const float* b1 = (const float*)d_in[4];
    const float* w2 = (const float*)d_in[5];
    const float* g2 = (const float*)d_in[6];
    const float* b2 = (const float*)d_in[7];
    const float* w3 = (const float*)d_in[8];
    const float* g3 = (const float*)d_in[9];
    const float* b3 = (const float*)d_in[10];
    const float* w4 = (const float*)d_in[11];
    const float* g4 = (const float*)d_in[12];
    const float* b4 = (const float*)d_in[13];
    float* out = (float*)d_out;

    char* w8 = (char*)d_ws;
    const size_t oB = 51480576;
    const size_t oT = oB + 12870144;
    const size_t STG = 6 * 64 * 2 * NREP * sizeof(float);   // 98304 B per stage
    __hip_bfloat16* conv1raw = (__hip_bfloat16*)(w8 + 0);
    float* conv2raw = (float*)(w8 + 0);
    float* conv3raw = (float*)(w8 + 0);
    __hip_bfloat16* act3 = (__hip_bfloat16*)(w8 + 6435072);
    float* conv4raw = (float*)(w8 + 9652608);
    __hip_bfloat16* fhat = (__hip_bfloat16*)(w8 + 16087680);
    __hip_bfloat16* pooled1 = (__hip_bfloat16*)(w8 + oB);     // 12.87MB
    __hip_bfloat16* pooled2 = (__hip_bfloat16*)(w8 + oB);     // reuse (3.2MB)
    float* sums = (float*)(w8 + oT);                          // 4 stages x 98304 B
    float* ms = (float*)(w8 + oT + 4 * STG);
    unsigned short* wpk2 = (unsigned short*)(w8 + oT + 4 * STG + 12288);
    unsigned short* wpk3 = (unsigned short*)(w8 + oT + 4 * STG + 12288 + 73728);
    unsigned short* wpk4 = (unsigned short*)(w8 + oT + 4 * STG + 12288 + 147456);
    if (ws_size < oT + 4 * STG + 12288 + 221184) return;
    float* sums1 = sums;
    float* sums2 = sums + 6 * 64 * 2 * NREP;
    float* sums3 = sums2 + 6 * 64 * 2 * NREP;
    float* sums4 = sums3 + 6 * 64 * 2 * NREP;

    hipMemsetAsync(d_out, 0, (size_t)out_size * sizeof(float), stream);
    hipMemsetAsync(sums, 0, 4 * STG, stream);

    pack_k<<<144, 256, 0, stream>>>(w2, wpk2);
    pack_k<<<144, 256, 0, stream>>>(w3, wpk3);
    pack_k<<<144, 256, 0, stream>>>(w4, wpk4);

    // stage 1: conv1 (+stats) -> finalize -> BN+LReLU+pool (84 -> 42)
    conv1_k<<<NIMG * 441, 256, 0, stream>>>(input1, input2, w1, conv1raw, sums1);
    finalize_k<<<2, 256, 0, stream>>>(sums1, ms + 0, g1, b1, P1);
    bnpool_k<__hip_bfloat16><<<25137, 256, 0, stream>>>(conv1raw, ms + 0, pooled1, 84);
    // stage 2: conv2 MFMA (+stats) -> finalize -> BN+LReLU+pool (42 -> 21)
    conv64m_k<42, 256><<<NIMG * 7, 256, 0, stream>>>((const unsigned short*)pooled1, wpk2, conv2raw, sums2);
    finalize_k<<<2, 256, 0, stream>>>(sums2, ms + 768, g2, b2, P2);
    bnpool_k<float><<<6285, 256, 0, stream>>>(conv2raw, ms + 768, pooled2, 42);
    // stage 3: conv3 MFMA (+stats) -> finalize -> BN+LReLU
    conv64m_k<21, 128><<<NIMG * 4, 256, 0, stream>>>((const unsigned short*)pooled2, wpk3, conv3raw, sums3);
    finalize_k<<<2, 256, 0, stream>>>(sums3, ms + 1536, g3, b3, P3);
    bnact_k<<<6285, 256, 0, stream>>>(conv3raw, ms + 1536, act3);
    // stage 4: conv4 MFMA (+stats) -> finalize -> BN+LReLU+normalize -> bf16 fhat
    conv64m_k<21, 128><<<NIMG * 4, 256, 0, stream>>>((const unsigned short*)act3, wpk4, conv4raw, sums4);
    finalize_k<<<2, 256, 0, stream>>>(sums4, ms + 2304, g4, b4, P3);
    bnnorm_k<<<6285, 256, 0, stream>>>(conv4raw, ms + 2304, fhat);
    // similarity + top-3 + sum
    sim_k<<<NQ * NCLS * 7, 256, 0, stream>>>(fhat, out);
}

// Round 5
// 267.447 us; speedup vs baseline: 13.6420x; 1.9037x over previous
//
#include <hip/hip_runtime.h>
#include <hip/hip_bf16.h>
#include <stdint.h>

#define NQ 32
#define NCLS 5
#define SHOT 5
#define NIMG 57          // 32 query + 25 support
#define P1 7056          // 84*84
#define P2 1764          // 42*42
#define P3 441           // 21*21
#define MM (SHOT*P3)     // 2205
#define EPSB 1e-5f
#define SLOPE 0.2f
#define NEGINF -3.4e38f
#define NREP 32          // stats atomic replication factor

typedef __attribute__((ext_vector_type(8))) short short8;
typedef __attribute__((ext_vector_type(4))) float f32x4;

__device__ inline float ldf(const float* p) { return *p; }
__device__ inline float ldf(const __hip_bfloat16* p) { return __bfloat162float(*p); }

__device__ __forceinline__ unsigned short bf16bits(float v)
{
    __hip_bfloat16 h = __float2bfloat16(v);
    return *reinterpret_cast<unsigned short*>(&h);
}

// ---------------- NCHW fp32 (3ch) -> channels-last [img][px][4] bf16 (ch3 = 0) ----------
__global__ __launch_bounds__(256) void nchw2cl_k(const float* __restrict__ in1,
                                                 const float* __restrict__ in2,
                                                 unsigned short* __restrict__ raw4)
{
    int idx = blockIdx.x * 256 + threadIdx.x;
    if (idx >= NIMG * P1) return;
    int img = idx / P1, p = idx - img * P1;
    const float* in = (img < NQ) ? in1 + (size_t)img * 3 * P1
                                 : in2 + (size_t)(img - NQ) * 3 * P1;
    union { unsigned short us[4]; uint2 u2; } o;
    o.us[0] = bf16bits(in[p]);
    o.us[1] = bf16bits(in[P1 + p]);
    o.us[2] = bf16bits(in[2 * P1 + p]);
    o.us[3] = 0;
    *(uint2*)(raw4 + (size_t)idx * 4) = o.u2;
}

// ---------------- conv1 weight pack: w1[64][3][3][3] -> 2 B-frag sets (K=32 each) --------
// ushort index: ((f*4 + nt)*64 + lane)*8 + j ; k = (lane>>4)*8 + j
// f0: t=k>>2 (taps 0..7), ci=k&3 (<3 real);  f1: only k<4 real -> tap 8, ci=k&3
__global__ void pack1_k(const float* __restrict__ w, unsigned short* __restrict__ wpk)
{
    int i = blockIdx.x * 256 + threadIdx.x;
    if (i >= 4096) return;
    int j = i & 7, lane = (i >> 3) & 63, c8 = i >> 9;
    int nt = c8 & 3, f = c8 >> 2;
    int co = nt * 16 + (lane & 15), q = lane >> 4;
    int k = q * 8 + j;
    float val = 0.f;
    if (f == 0) {
        int t = k >> 2, ci = k & 3;
        if (ci < 3) val = w[co * 27 + ci * 9 + t];
    } else if (k < 4) {
        int ci = k & 3;
        if (ci < 3) val = w[co * 27 + ci * 9 + 8];
    }
    wpk[i] = bf16bits(val);
}

// ---------------- MFMA conv1 3->64 on [px][4] bf16, fused BN stats, bf16 out ----------
__global__ __launch_bounds__(256) void conv1m_k(const unsigned short* __restrict__ raw4,
                                                const unsigned short* __restrict__ wpk1,
                                                __hip_bfloat16* __restrict__ out,
                                                float* __restrict__ sums)
{
    constexpr int S = 84, P = P1, MBLK = 256, NB = 28, SPAN = MBLK + 2 * S + 2;  // 426
    __shared__ __align__(16) unsigned short ls4[SPAN * 4];   // 8 B per pixel
    __shared__ float qs[4][64], qs2[4][64];
    int img = blockIdx.x / NB;
    int p0 = (blockIdx.x % NB) * MBLK;
    int tid = threadIdx.x, lane = tid & 63, wv = tid >> 6;
    int col = lane & 15, quad = lane >> 4;
    const unsigned short* ib = raw4 + (size_t)img * P * 4;
    for (int u = tid; u < SPAN; u += 256) {
        int p = p0 - S - 1 + u;
        uint2 v = {0u, 0u};
        if (p >= 0 && p < P) v = *(const uint2*)(ib + (size_t)p * 4);
        *(uint2*)(ls4 + u * 4) = v;
    }
    // B fragments (global, L2-hot, 8 KB)
    const short8* wb = (const short8*)wpk1;
    short8 b0[4], b1[4];
    #pragma unroll
    for (int nt = 0; nt < 4; ++nt) {
        b0[nt] = wb[(size_t)(nt * 64 + lane)];
        b1[nt] = wb[(size_t)((4 + nt) * 64 + lane)];
    }
    // this quad's taps for frag0: t0=2q, t1=2q+1 ; frag1: tap 8 (quad 0 only)
    int t0 = 2 * quad, t1 = t0 + 1;
    int d0 = (t0 / 3 - 1) * S + (t0 % 3 - 1);
    int d1 = (t1 / 3 - 1) * S + (t1 % 3 - 1);
    const int d8 = S + 1;                       // tap 8: (+1,+1)
    int tx0 = t0 % 3, tx1 = t1 % 3;
    __syncthreads();
    f32x4 acc[4][4];
    #pragma unroll
    for (int mt = 0; mt < 4; ++mt)
        #pragma unroll
        for (int nt = 0; nt < 4; ++nt) acc[mt][nt] = (f32x4){0.f, 0.f, 0.f, 0.f};
    #pragma unroll
    for (int mt = 0; mt < 4; ++mt) {
        int pl = wv * 64 + mt * 16 + col;       // pixel offset within block (A row m)
        int xm = (p0 + pl) % S;
        int base = pl + S + 1;
        uint2 h0 = *(const uint2*)(ls4 + (base + d0) * 4);
        uint2 h1 = *(const uint2*)(ls4 + (base + d1) * 4);
        uint2 h8 = *(const uint2*)(ls4 + (base + d8) * 4);
        bool ok0 = (tx0 == 0) ? (xm >= 1) : ((tx0 == 2) ? (xm <= S - 2) : true);
        bool ok1 = (tx1 == 0) ? (xm >= 1) : ((tx1 == 2) ? (xm <= S - 2) : true);
        bool ok8 = (quad == 0) && (xm <= S - 2);
        if (!ok0) h0 = (uint2){0u, 0u};
        if (!ok1) h1 = (uint2){0u, 0u};
        if (!ok8) h8 = (uint2){0u, 0u};
        union { uint4 u; short8 s; } ca, cb;
        ca.u = (uint4){h0.x, h0.y, h1.x, h1.y};
        cb.u = (uint4){h8.x, h8.y, 0u, 0u};
        #pragma unroll
        for (int nt = 0; nt < 4; ++nt) {
            acc[mt][nt] = __builtin_amdgcn_mfma_f32_16x16x32_bf16(ca.s, b0[nt], acc[mt][nt], 0, 0, 0);
            acc[mt][nt] = __builtin_amdgcn_mfma_f32_16x16x32_bf16(cb.s, b1[nt], acc[mt][nt], 0, 0, 0);
        }
    }
    float s[4] = {0.f, 0.f, 0.f, 0.f}, s2[4] = {0.f, 0.f, 0.f, 0.f};
    __hip_bfloat16* ob = out + (size_t)img * P * 64;
    #pragma unroll
    for (int mt = 0; mt < 4; ++mt) {
        int tb = p0 + wv * 64 + mt * 16 + quad * 4;
        #pragma unroll
        for (int reg = 0; reg < 4; ++reg) {
            int pr = tb + reg;
            if (pr < P) {
                #pragma unroll
                for (int nt = 0; nt < 4; ++nt) {
                    float v = acc[mt][nt][reg];
                    ob[(size_t)pr * 64 + nt * 16 + col] = __float2bfloat16(v);
                    s[nt] += v;
                    s2[nt] = fmaf(v, v, s2[nt]);
                }
            }
        }
    }
    #pragma unroll
    for (int d = 16; d < 64; d <<= 1)
        #pragma unroll
        for (int nt = 0; nt < 4; ++nt) {
            s[nt] += __shfl_xor(s[nt], d, 64);
            s2[nt] += __shfl_xor(s2[nt], d, 64);
        }
    if (quad == 0) {
        #pragma unroll
        for (int nt = 0; nt < 4; ++nt) {
            qs[wv][nt * 16 + col] = s[nt];
            qs2[wv][nt * 16 + col] = s2[nt];
        }
    }
    __syncthreads();
    if (wv == 0) {
        int g = (img < NQ) ? 0 : 1 + (img - NQ) / SHOT;
        int rep = blockIdx.x & (NREP - 1);
        float ts = qs[0][lane] + qs[1][lane] + qs[2][lane] + qs[3][lane];
        float ts2 = qs2[0][lane] + qs2[1][lane] + qs2[2][lane] + qs2[3][lane];
        float* base = sums + ((size_t)(g * 64 + lane) * 2) * NREP + rep;
        atomicAdd(base, ts);
        atomicAdd(base + NREP, ts2);
    }
}

// ---------------- weight pack: w[co][ci][3][3] fp32 -> B-fragment-ordered bf16 ----------------
__global__ void pack_k(const float* __restrict__ w, unsigned short* __restrict__ wpk)
{
    int i = blockIdx.x * 256 + threadIdx.x;
    if (i >= 36864) return;
    int j = i & 7, lane = (i >> 3) & 63, chunk = i >> 9;
    int nt = chunk & 3, half = (chunk >> 2) & 1, t = chunk >> 3;
    int co = nt * 16 + (lane & 15);
    int ci = half * 32 + (lane >> 4) * 8 + j;
    wpk[i] = bf16bits(w[co * 576 + ci * 9 + t]);
}

// ---------------- MFMA conv 64->64, channels-last bf16 in, fp32 out, fused BN stats ----------
template <int S, int MBLK>
__global__ __launch_bounds__(256) void conv64m_k(const unsigned short* __restrict__ in,
                                                 const unsigned short* __restrict__ wpk,
                                                 float* __restrict__ out,
                                                 float* __restrict__ sums)
{
    constexpr int P = S * S;
    constexpr int MT = MBLK / 64;          // m-tiles per wave
    constexpr int NB = (P + MBLK - 1) / MBLK;
    constexpr int SPAN = MBLK + 2 * S + 2;
    __shared__ __align__(16) unsigned short ls[SPAN * 72];   // 72-ushort padded pixel rows
    __shared__ float qs[4][64], qs2[4][64];
    int img = blockIdx.x / NB;
    int p0 = (blockIdx.x % NB) * MBLK;
    int tid = threadIdx.x;
    int lane = tid & 63, wv = tid >> 6;
    int col = lane & 15, quad = lane >> 4;
    const unsigned short* ib = in + (size_t)img * P * 64;
    for (int u = tid; u < SPAN * 8; u += 256) {
        int pix = u >> 3, part = u & 7;
        int p = p0 - S - 1 + pix;
        short8 v = {0, 0, 0, 0, 0, 0, 0, 0};
        if (p >= 0 && p < P) v = *(const short8*)(ib + (size_t)p * 64 + part * 8);
        *(short8*)(ls + pix * 72 + part * 8) = v;
    }
    __syncthreads();
    f32x4 acc[MT][4];
    #pragma unroll
    for (int mt = 0; mt < MT; ++mt)
        #pragma unroll
        for (int nt = 0; nt < 4; ++nt) acc[mt][nt] = (f32x4){0.f, 0.f, 0.f, 0.f};
    bool mok0[MT], mok2[MT];
    #pragma unroll
    for (int mt = 0; mt < MT; ++mt) {
        int xm = (p0 + wv * (MT * 16) + mt * 16 + col) % S;
        mok0[mt] = xm >= 1;
        mok2[mt] = xm <= S - 2;
    }
    const short8* wb = (const short8*)wpk;
    #pragma unroll
    for (int ky = 0; ky < 3; ++ky) {
        #pragma unroll
        for (int kx = 0; kx < 3; ++kx) {
            int t = ky * 3 + kx;
            int d = (ky - 1) * S + (kx - 1);
            #pragma unroll
            for (int half = 0; half < 2; ++half) {
                short8 b[4];
                #pragma unroll
                for (int nt = 0; nt < 4; ++nt)
                    b[nt] = wb[((t * 2 + half) * 4 + nt) * 64 + lane];
                #pragma unroll
                for (int mt = 0; mt < MT; ++mt) {
                    int idx = wv * (MT * 16) + mt * 16 + col + S + 1 + d;
                    short8 a = *(const short8*)(ls + idx * 72 + half * 32 + quad * 8);
                    bool ok = (kx == 0) ? mok0[mt] : (kx == 2) ? mok2[mt] : true;
                    if (!ok) a = (short8){0, 0, 0, 0, 0, 0, 0, 0};
                    #pragma unroll
                    for (int nt = 0; nt < 4; ++nt)
                        acc[mt][nt] = __builtin_amdgcn_mfma_f32_16x16x32_bf16(a, b[nt], acc[mt][nt], 0, 0, 0);
                }
            }
        }
    }
    float s[4] = {0.f, 0.f, 0.f, 0.f}, s2[4] = {0.f, 0.f, 0.f, 0.f};
    float* ob = out + (size_t)img * P * 64;
    #pragma unroll
    for (int mt = 0; mt < MT; ++mt) {
        int tb = p0 + wv * (MT * 16) + mt * 16 + quad * 4;
        #pragma unroll
        for (int reg = 0; reg < 4; ++reg) {
            int pr = tb + reg;
            if (pr < P) {
                #pragma unroll
                for (int nt = 0; nt < 4; ++nt) {
                    float v = acc[mt][nt][reg];
                    ob[(size_t)pr * 64 + nt * 16 + col] = v;
                    s[nt] += v;
                    s2[nt] = fmaf(v, v, s2[nt]);
                }
            }
        }
    }
    #pragma unroll
    for (int d = 16; d < 64; d <<= 1)
        #pragma unroll
        for (int nt = 0; nt < 4; ++nt) {
            s[nt] += __shfl_xor(s[nt], d, 64);
            s2[nt] += __shfl_xor(s2[nt], d, 64);
        }
    if (quad == 0) {
        #pragma unroll
        for (int nt = 0; nt < 4; ++nt) {
            qs[wv][nt * 16 + col] = s[nt];
            qs2[wv][nt * 16 + col] = s2[nt];
        }
    }
    __syncthreads();
    if (wv == 0) {
        int g = (img < NQ) ? 0 : 1 + (img - NQ) / SHOT;
        int rep = blockIdx.x & (NREP - 1);
        float ts = qs[0][lane] + qs[1][lane] + qs[2][lane] + qs[3][lane];
        float ts2 = qs2[0][lane] + qs2[1][lane] + qs2[2][lane] + qs2[3][lane];
        float* base = sums + ((size_t)(g * 64 + lane) * 2) * NREP + rep;
        atomicAdd(base, ts);
        atomicAdd(base + NREP, ts2);
    }
}

// fold (mean, invstd, gamma, beta) -> (a, b): y = x*a + b   (sums has NREP replicas)
__global__ void finalize_k(const float* __restrict__ sums, float* __restrict__ ms,
                           const float* __restrict__ gamma, const float* __restrict__ beta, int P)
{
    int i = blockIdx.x * blockDim.x + threadIdx.x;
    if (i >= 6 * 64) return;
    int g = i >> 6, c = i & 63;
    const float* ps = sums + (size_t)i * 2 * NREP;
    float s = 0.f, s2 = 0.f;
    #pragma unroll
    for (int r = 0; r < NREP; ++r) { s += ps[r]; s2 += ps[NREP + r]; }
    float cnt = (float)((g == 0 ? NQ : SHOT) * P);
    float mean = s / cnt;
    float var = s2 / cnt - mean * mean;
    float a = rsqrtf(var + EPSB) * gamma[c];
    ms[i * 2] = a;
    ms[i * 2 + 1] = fmaf(-mean, a, beta[c]);
}

// ---------------- BN + LeakyReLU + 2x2 maxpool -> bf16 ----------------
template <typename T>
__global__ __launch_bounds__(256) void bnpool_k(const T* __restrict__ x, const float* __restrict__ ms,
                                                __hip_bfloat16* __restrict__ out, int Win)
{
    int Wout = Win >> 1, Pout = Wout * Wout;
    size_t idx = (size_t)blockIdx.x * 256 + threadIdx.x;
    size_t total = (size_t)NIMG * Pout * 64;
    if (idx >= total) return;
    int c = (int)(idx & 63);
    size_t t = idx >> 6;
    int p = (int)(t % Pout);
    int img = (int)(t / Pout);
    int y = p / Wout, xo = p - y * Wout;
    int g = (img < NQ) ? 0 : 1 + (img - NQ) / SHOT;
    float a = ms[(g * 64 + c) * 2], bb = ms[(g * 64 + c) * 2 + 1];
    const T* base = x + (((size_t)img * Win + 2 * y) * Win + 2 * xo) * 64 + c;
    float mx = -3.4e38f;
    #pragma unroll
    for (int dy = 0; dy < 2; ++dy)
        #pragma unroll
        for (int dx = 0; dx < 2; ++dx) {
            float v = ldf(base + ((size_t)dy * Win + dx) * 64);
            v = fmaf(v, a, bb);
            v = v >= 0.f ? v : SLOPE * v;
            mx = fmaxf(mx, v);
        }
    out[idx] = __float2bfloat16(mx);
}

// ---------------- BN + LeakyReLU (elementwise, stage 3) -> bf16 ----------------
__global__ __launch_bounds__(256) void bnact_k(const float* __restrict__ x, const float* __restrict__ ms,
                                               __hip_bfloat16* __restrict__ out)
{
    size_t idx = (size_t)blockIdx.x * 256 + threadIdx.x;
    size_t total = (size_t)NIMG * P3 * 64;
    if (idx >= total) return;
    int c = (int)(idx & 63);
    int img = (int)(idx >> 6) / P3;
    int g = (img < NQ) ? 0 : 1 + (img - NQ) / SHOT;
    float v = fmaf(x[idx], ms[(g * 64 + c) * 2], ms[(g * 64 + c) * 2 + 1]);
    out[idx] = __float2bfloat16(v >= 0.f ? v : SLOPE * v);
}

// ---------------- BN4 + LeakyReLU + per-pixel L2-normalize -> bf16 ----------------
__global__ __launch_bounds__(256) void bnnorm_k(const float* __restrict__ x, const float* __restrict__ ms,
                                                __hip_bfloat16* __restrict__ out)
{
    int lane = threadIdx.x & 63, wvr = threadIdx.x >> 6;
    int pix = blockIdx.x * 4 + wvr;        // one wave per pixel
    if (pix >= NIMG * P3) return;
    int img = pix / P3;
    int g = (img < NQ) ? 0 : 1 + (img - NQ) / SHOT;
    float v = fmaf(x[(size_t)pix * 64 + lane], ms[(g * 64 + lane) * 2], ms[(g * 64 + lane) * 2 + 1]);
    v = v >= 0.f ? v : SLOPE * v;
    float ss = v * v;
    #pragma unroll
    for (int d = 32; d > 0; d >>= 1) ss += __shfl_xor(ss, d, 64);
    out[(size_t)pix * 64 + lane] = __float2bfloat16(v * rsqrtf(ss));
}

// ---------------- similarity: MFMA bf16, branchless per-lane top-3, shfl merge ----------------
__device__ __forceinline__ void ins3(float v, float& t0, float& t1, float& t2)
{
    float n1 = __builtin_amdgcn_fmed3f(v, t0, t1);
    float n2 = __builtin_amdgcn_fmed3f(v, t1, t2);
    t0 = fmaxf(t0, v);
    t1 = n1;
    t2 = n2;
}

__global__ __launch_bounds__(256) void sim_k(const __hip_bfloat16* __restrict__ fhat,
                                             float* __restrict__ out)
{
    __shared__ __align__(16) unsigned short sl[64 * 72];   // 64 m-rows, 72-ushort stride
    int t = blockIdx.x;
    int qb = t % 7;
    int n = (t / 7) % NCLS;
    int bq = t / (7 * NCLS);
    int lane = threadIdx.x & 63, wv = threadIdx.x >> 6;
    int col = lane & 15, quad = lane >> 4;
    int q = qb * 64 + wv * 16 + col;
    int qc = q < P3 ? q : P3 - 1;
    const unsigned short* qp = (const unsigned short*)fhat + ((size_t)bq * P3 + qc) * 64;
    short8 a0 = *(const short8*)(qp + quad * 8);
    short8 a1 = *(const short8*)(qp + 32 + quad * 8);
    const unsigned short* sp = (const unsigned short*)fhat + (size_t)(NQ + n * SHOT) * P3 * 64;
    float t0[4], t1[4], t2[4];
    #pragma unroll
    for (int i = 0; i < 4; ++i) { t0[i] = NEGINF; t1[i] = NEGINF; t2[i] = NEGINF; }
    for (int mc = 0; mc < 35; ++mc) {
        int m0 = mc * 64;
        __syncthreads();
        #pragma unroll
        for (int pass = 0; pass < 2; ++pass) {
            int row = (threadIdx.x >> 3) + pass * 32;
            int cc = (threadIdx.x & 7) * 8;
            int m = m0 + row;
            short8 vv = {0, 0, 0, 0, 0, 0, 0, 0};
            if (m < MM) vv = *(const short8*)(sp + (size_t)m * 64 + cc);
            *(short8*)(sl + row * 72 + cc) = vv;
        }
        __syncthreads();
        #pragma unroll
        for (int mt = 0; mt < 4; ++mt) {
            const unsigned short* sr = sl + (mt * 16 + col) * 72;
            short8 b0 = *(const short8*)(sr + quad * 8);
            short8 b1 = *(const short8*)(sr + 32 + quad * 8);
            f32x4 acc = {0.f, 0.f, 0.f, 0.f};
            acc = __builtin_amdgcn_mfma_f32_16x16x32_bf16(a0, b0, acc, 0, 0, 0);
            acc = __builtin_amdgcn_mfma_f32_16x16x32_bf16(a1, b1, acc, 0, 0, 0);
            if (m0 + mt * 16 + 15 < MM) {
                #pragma unroll
                for (int i = 0; i < 4; ++i) ins3(acc[i], t0[i], t1[i], t2[i]);
            } else {
                float bias = (m0 + mt * 16 + col < MM) ? 0.f : NEGINF;
                #pragma unroll
                for (int i = 0; i < 4; ++i) ins3(acc[i] + bias, t0[i], t1[i], t2[i]);
            }
        }
    }
    #pragma unroll
    for (int d = 1; d < 16; d <<= 1) {
        #pragma unroll
        for (int i = 0; i < 4; ++i) {
            float u0 = __shfl_xor(t0[i], d, 64);
            float u1 = __shfl_xor(t1[i], d, 64);
            float u2 = __shfl_xor(t2[i], d, 64);
            ins3(u0, t0[i], t1[i], t2[i]);
            ins3(u1, t0[i], t1[i], t2[i]);
            ins3(u2, t0[i], t1[i], t2[i]);
        }
    }
    if (col == 0) {
        float s = 0.f;
        int q0 = qb * 64 + wv * 16 + quad * 4;
        #pragma unroll
        for (int i = 0; i < 4; ++i)
            if (q0 + i < P3) s += t0[i] + t1[i] + t2[i];
        atomicAdd(&out[bq * NCLS + n], s);
    }
}

extern "C" void kernel_launch(void* const* d_in, const int* in_sizes, int n_in,
                              void* d_out, int out_size, void* d_ws, size_t ws_size,
                              hipStream_t stream)
{
    const float* input1 = (const float*)d_in[0];
    const float* input2 = (const float*)d_in[1];
    const float* w1 = (const float*)d_in[2];
    const float* g1 = (const float*)d_in[3];
    const float* b1 = (const float*)d_in[4];
    const float* w2 = (const float*)d_in[5];
    const float* g2 = (const float*)d_in[6];
    const float* b2 = (const float*)d_in[7];
    const float* w3 = (const float*)d_in[8];
    const float* g3 = (const float*)d_in[9];
    const float* b3 = (const float*)d_in[10];
    const float* w4 = (const float*)d_in[11];
    const float* g4 = (const float*)d_in[12];
    const float* b4 = (const float*)d_in[13];
    float* out = (float*)d_out;

    char* w8 = (char*)d_ws;
    const size_t oB = 51480576;
    const size_t oT = oB + 12870144;
    const size_t STG = 6 * 64 * 2 * NREP * sizeof(float);   // 98304 B per stage
    __hip_bfloat16* conv1raw = (__hip_bfloat16*)(w8 + 0);
    float* conv2raw = (float*)(w8 + 0);
    float* conv3raw = (float*)(w8 + 0);
    __hip_bfloat16* act3 = (__hip_bfloat16*)(w8 + 6435072);
    float* conv4raw = (float*)(w8 + 9652608);
    __hip_bfloat16* fhat = (__hip_bfloat16*)(w8 + 16087680);
    unsigned short* raw4 = (unsigned short*)(w8 + oB);        // 3.2MB, dead before pooled1 written
    __hip_bfloat16* pooled1 = (__hip_bfloat16*)(w8 + oB);     // 12.87MB
    __hip_bfloat16* pooled2 = (__hip_bfloat16*)(w8 + oB);     // reuse (3.2MB)
    float* sums = (float*)(w8 + oT);                          // 4 stages x 98304 B
    float* ms = (float*)(w8 + oT + 4 * STG);
    unsigned short* wpk2 = (unsigned short*)(w8 + oT + 4 * STG + 12288);
    unsigned short* wpk3 = (unsigned short*)(w8 + oT + 4 * STG + 12288 + 73728);
    unsigned short* wpk4 = (unsigned short*)(w8 + oT + 4 * STG + 12288 + 147456);
    unsigned short* wpk1 = (unsigned short*)(w8 + oT + 4 * STG + 12288 + 221184);
    if (ws_size < oT + 4 * STG + 12288 + 221184 + 8192) return;
    float* sums1 = sums;
    float* sums2 = sums + 6 * 64 * 2 * NREP;
    float* sums3 = sums2 + 6 * 64 * 2 * NREP;
    float* sums4 = sums3 + 6 * 64 * 2 * NREP;

    hipMemsetAsync(d_out, 0, (size_t)out_size * sizeof(float), stream);
    hipMemsetAsync(sums, 0, 4 * STG, stream);

    pack1_k<<<16, 256, 0, stream>>>(w1, wpk1);
    pack_k<<<144, 256, 0, stream>>>(w2, wpk2);
    pack_k<<<144, 256, 0, stream>>>(w3, wpk3);
    pack_k<<<144, 256, 0, stream>>>(w4, wpk4);

    // stage 1: nchw->cl, conv1 MFMA (+stats) -> finalize -> BN+LReLU+pool (84 -> 42)
    nchw2cl_k<<<(NIMG * P1 + 255) / 256, 256, 0, stream>>>(input1, input2, raw4);
    conv1m_k<<<NIMG * 28, 256, 0, stream>>>(raw4, wpk1, conv1raw, sums1);
    finalize_k<<<2, 256, 0, stream>>>(sums1, ms + 0, g1, b1, P1);
    bnpool_k<__hip_bfloat16><<<25137, 256, 0, stream>>>(conv1raw, ms + 0, pooled1, 84);
    // stage 2: conv2 MFMA (+stats) -> finalize -> BN+LReLU+pool (42 -> 21)
    conv64m_k<42, 256><<<NIMG * 7, 256, 0, stream>>>((const unsigned short*)pooled1, wpk2, conv2raw, sums2);
    finalize_k<<<2, 256, 0, stream>>>(sums2, ms + 768, g2, b2, P2);
    bnpool_k<float><<<6285, 256, 0, stream>>>(conv2raw, ms + 768, pooled2, 42);
    // stage 3: conv3 MFMA (+stats) -> finalize -> BN+LReLU
    conv64m_k<21, 128><<<NIMG * 4, 256, 0, stream>>>((const unsigned short*)pooled2, wpk3, conv3raw, sums3);
    finalize_k<<<2, 256, 0, stream>>>(sums3, ms + 1536, g3, b3, P3);
    bnact_k<<<6285, 256, 0, stream>>>(conv3raw, ms + 1536, act3);
    // stage 4: conv4 MFMA (+stats) -> finalize -> BN+LReLU+normalize -> bf16 fhat
    conv64m_k<21, 128><<<NIMG * 4, 256, 0, stream>>>((const unsigned short*)act3, wpk4, conv4raw, sums4);
    finalize_k<<<2, 256, 0, stream>>>(sums4, ms + 2304, g4, b4, P3);
    bnnorm_k<<<6285, 256, 0, stream>>>(conv4raw, ms + 2304, fhat);
    // similarity + top-3 + sum
    sim_k<<<NQ * NCLS * 7, 256, 0, stream>>>(fhat, out);
}

// Round 6
// 262.102 us; speedup vs baseline: 13.9202x; 1.0204x over previous
//
#include <hip/hip_runtime.h>
#include <hip/hip_bf16.h>
#include <stdint.h>

#define NQ 32
#define NCLS 5
#define SHOT 5
#define NIMG 57          // 32 query + 25 support
#define P1 7056          // 84*84
#define P2 1764          // 42*42
#define P3 441           // 21*21
#define MM (SHOT*P3)     // 2205
#define EPSB 1e-5f
#define SLOPE 0.2f
#define NEGINF -3.4e38f
#define NREP 32          // stats atomic replication factor
#define MCH 18           // sim_k m-chunks of 128 rows (pad 2205 -> 2304)

typedef __attribute__((ext_vector_type(8))) short short8;
typedef __attribute__((ext_vector_type(4))) float f32x4;

__device__ inline float ldf(const float* p) { return *p; }
__device__ inline float ldf(const __hip_bfloat16* p) { return __bfloat162float(*p); }

__device__ __forceinline__ unsigned short bf16bits(float v)
{
    __hip_bfloat16 h = __float2bfloat16(v);
    return *reinterpret_cast<unsigned short*>(&h);
}

// ---------------- all weight packs in one launch ----------------
// sets 0..2: w2/w3/w4 64->64 pack (36864 ushorts each)
//   idx: ((t*2+half)*4+nt)*512 + lane*8 + j ; co=nt*16+(lane&15), ci=half*32+(lane>>4)*8+j
// set 3: conv1 pack (4096 ushorts): ((f*4+nt)*64+lane)*8+j ; k=(lane>>4)*8+j
__global__ void pack_all_k(const float* __restrict__ w1, const float* __restrict__ w2,
                           const float* __restrict__ w3, const float* __restrict__ w4,
                           unsigned short* __restrict__ wpk1, unsigned short* __restrict__ wpk2,
                           unsigned short* __restrict__ wpk3, unsigned short* __restrict__ wpk4)
{
    int i = blockIdx.x * 256 + threadIdx.x;
    if (i < 3 * 36864) {
        int set = i / 36864, ii = i - set * 36864;
        const float* w = (set == 0) ? w2 : (set == 1) ? w3 : w4;
        unsigned short* wpk = (set == 0) ? wpk2 : (set == 1) ? wpk3 : wpk4;
        int j = ii & 7, lane = (ii >> 3) & 63, chunk = ii >> 9;
        int nt = chunk & 3, half = (chunk >> 2) & 1, t = chunk >> 3;
        int co = nt * 16 + (lane & 15);
        int ci = half * 32 + (lane >> 4) * 8 + j;
        wpk[ii] = bf16bits(w[co * 576 + ci * 9 + t]);
    } else {
        int ii = i - 3 * 36864;
        if (ii >= 4096) return;
        int j = ii & 7, lane = (ii >> 3) & 63, c8 = ii >> 9;
        int nt = c8 & 3, f = c8 >> 2;
        int co = nt * 16 + (lane & 15), q = lane >> 4;
        int k = q * 8 + j;
        float val = 0.f;
        if (f == 0) {
            int t = k >> 2, ci = k & 3;
            if (ci < 3) val = w1[co * 27 + ci * 9 + t];
        } else if (k < 4) {
            int ci = k & 3;
            if (ci < 3) val = w1[co * 27 + ci * 9 + 8];
        }
        wpk1[ii] = bf16bits(val);
    }
}

// ---------------- MFMA conv1 3->64, stages NCHW fp32 directly, fused BN stats, bf16 out ----
__global__ __launch_bounds__(256) void conv1m_k(const float* __restrict__ in1,
                                                const float* __restrict__ in2,
                                                const unsigned short* __restrict__ wpk1,
                                                __hip_bfloat16* __restrict__ out,
                                                float* __restrict__ sums)
{
    constexpr int S = 84, P = P1, MBLK = 256, NB = 28, SPAN = MBLK + 2 * S + 2;  // 426
    __shared__ __align__(16) unsigned short ls4[SPAN * 4];   // 8 B per pixel [c0,c1,c2,0]
    __shared__ float qs[4][64], qs2[4][64];
    int img = blockIdx.x / NB;
    int p0 = (blockIdx.x % NB) * MBLK;
    int tid = threadIdx.x, lane = tid & 63, wv = tid >> 6;
    int col = lane & 15, quad = lane >> 4;
    const float* in = (img < NQ) ? in1 + (size_t)img * 3 * P1
                                 : in2 + (size_t)(img - NQ) * 3 * P1;
    for (int u = tid; u < SPAN; u += 256) {
        int p = p0 - S - 1 + u;
        union { unsigned short us[4]; uint2 u2; } o;
        o.u2 = (uint2){0u, 0u};
        if (p >= 0 && p < P) {
            o.us[0] = bf16bits(in[p]);
            o.us[1] = bf16bits(in[P1 + p]);
            o.us[2] = bf16bits(in[2 * P1 + p]);
        }
        *(uint2*)(ls4 + u * 4) = o.u2;
    }
    // B fragments (global, L2-hot, 8 KB)
    const short8* wb = (const short8*)wpk1;
    short8 b0[4], b1[4];
    #pragma unroll
    for (int nt = 0; nt < 4; ++nt) {
        b0[nt] = wb[(size_t)(nt * 64 + lane)];
        b1[nt] = wb[(size_t)((4 + nt) * 64 + lane)];
    }
    int t0 = 2 * quad, t1 = t0 + 1;
    int d0 = (t0 / 3 - 1) * S + (t0 % 3 - 1);
    int d1 = (t1 / 3 - 1) * S + (t1 % 3 - 1);
    const int d8 = S + 1;
    int tx0 = t0 % 3, tx1 = t1 % 3;
    __syncthreads();
    f32x4 acc[4][4];
    #pragma unroll
    for (int mt = 0; mt < 4; ++mt)
        #pragma unroll
        for (int nt = 0; nt < 4; ++nt) acc[mt][nt] = (f32x4){0.f, 0.f, 0.f, 0.f};
    #pragma unroll
    for (int mt = 0; mt < 4; ++mt) {
        int pl = wv * 64 + mt * 16 + col;
        int xm = (p0 + pl) % S;
        int base = pl + S + 1;
        uint2 h0 = *(const uint2*)(ls4 + (base + d0) * 4);
        uint2 h1 = *(const uint2*)(ls4 + (base + d1) * 4);
        uint2 h8 = *(const uint2*)(ls4 + (base + d8) * 4);
        bool ok0 = (tx0 == 0) ? (xm >= 1) : ((tx0 == 2) ? (xm <= S - 2) : true);
        bool ok1 = (tx1 == 0) ? (xm >= 1) : ((tx1 == 2) ? (xm <= S - 2) : true);
        bool ok8 = (quad == 0) && (xm <= S - 2);
        if (!ok0) h0 = (uint2){0u, 0u};
        if (!ok1) h1 = (uint2){0u, 0u};
        if (!ok8) h8 = (uint2){0u, 0u};
        union { uint4 u; short8 s; } ca, cb;
        ca.u = (uint4){h0.x, h0.y, h1.x, h1.y};
        cb.u = (uint4){h8.x, h8.y, 0u, 0u};
        #pragma unroll
        for (int nt = 0; nt < 4; ++nt) {
            acc[mt][nt] = __builtin_amdgcn_mfma_f32_16x16x32_bf16(ca.s, b0[nt], acc[mt][nt], 0, 0, 0);
            acc[mt][nt] = __builtin_amdgcn_mfma_f32_16x16x32_bf16(cb.s, b1[nt], acc[mt][nt], 0, 0, 0);
        }
    }
    float s[4] = {0.f, 0.f, 0.f, 0.f}, s2[4] = {0.f, 0.f, 0.f, 0.f};
    __hip_bfloat16* ob = out + (size_t)img * P * 64;
    #pragma unroll
    for (int mt = 0; mt < 4; ++mt) {
        int tb = p0 + wv * 64 + mt * 16 + quad * 4;
        #pragma unroll
        for (int reg = 0; reg < 4; ++reg) {
            int pr = tb + reg;
            if (pr < P) {
                #pragma unroll
                for (int nt = 0; nt < 4; ++nt) {
                    float v = acc[mt][nt][reg];
                    ob[(size_t)pr * 64 + nt * 16 + col] = __float2bfloat16(v);
                    s[nt] += v;
                    s2[nt] = fmaf(v, v, s2[nt]);
                }
            }
        }
    }
    #pragma unroll
    for (int d = 16; d < 64; d <<= 1)
        #pragma unroll
        for (int nt = 0; nt < 4; ++nt) {
            s[nt] += __shfl_xor(s[nt], d, 64);
            s2[nt] += __shfl_xor(s2[nt], d, 64);
        }
    if (quad == 0) {
        #pragma unroll
        for (int nt = 0; nt < 4; ++nt) {
            qs[wv][nt * 16 + col] = s[nt];
            qs2[wv][nt * 16 + col] = s2[nt];
        }
    }
    __syncthreads();
    if (wv == 0) {
        int g = (img < NQ) ? 0 : 1 + (img - NQ) / SHOT;
        int rep = blockIdx.x & (NREP - 1);
        float ts = qs[0][lane] + qs[1][lane] + qs[2][lane] + qs[3][lane];
        float ts2 = qs2[0][lane] + qs2[1][lane] + qs2[2][lane] + qs2[3][lane];
        float* base = sums + ((size_t)(g * 64 + lane) * 2) * NREP + rep;
        atomicAdd(base, ts);
        atomicAdd(base + NREP, ts2);
    }
}

// ---------------- MFMA conv 64->64, channels-last bf16 in, fp32 out, fused BN stats ----------
template <int S, int MBLK>
__global__ __launch_bounds__(256) void conv64m_k(const unsigned short* __restrict__ in,
                                                 const unsigned short* __restrict__ wpk,
                                                 float* __restrict__ out,
                                                 float* __restrict__ sums)
{
    constexpr int P = S * S;
    constexpr int MT = MBLK / 64;          // m-tiles per wave
    constexpr int NB = (P + MBLK - 1) / MBLK;
    constexpr int SPAN = MBLK + 2 * S + 2;
    __shared__ __align__(16) unsigned short ls[SPAN * 72];   // 72-ushort padded pixel rows
    __shared__ float qs[4][64], qs2[4][64];
    int img = blockIdx.x / NB;
    int p0 = (blockIdx.x % NB) * MBLK;
    int tid = threadIdx.x;
    int lane = tid & 63, wv = tid >> 6;
    int col = lane & 15, quad = lane >> 4;
    const unsigned short* ib = in + (size_t)img * P * 64;
    for (int u = tid; u < SPAN * 8; u += 256) {
        int pix = u >> 3, part = u & 7;
        int p = p0 - S - 1 + pix;
        short8 v = {0, 0, 0, 0, 0, 0, 0, 0};
        if (p >= 0 && p < P) v = *(const short8*)(ib + (size_t)p * 64 + part * 8);
        *(short8*)(ls + pix * 72 + part * 8) = v;
    }
    __syncthreads();
    f32x4 acc[MT][4];
    #pragma unroll
    for (int mt = 0; mt < MT; ++mt)
        #pragma unroll
        for (int nt = 0; nt < 4; ++nt) acc[mt][nt] = (f32x4){0.f, 0.f, 0.f, 0.f};
    bool mok0[MT], mok2[MT];
    #pragma unroll
    for (int mt = 0; mt < MT; ++mt) {
        int xm = (p0 + wv * (MT * 16) + mt * 16 + col) % S;
        mok0[mt] = xm >= 1;
        mok2[mt] = xm <= S - 2;
    }
    const short8* wb = (const short8*)wpk;
    #pragma unroll
    for (int ky = 0; ky < 3; ++ky) {
        #pragma unroll
        for (int kx = 0; kx < 3; ++kx) {
            int t = ky * 3 + kx;
            int d = (ky - 1) * S + (kx - 1);
            #pragma unroll
            for (int half = 0; half < 2; ++half) {
                short8 b[4];
                #pragma unroll
                for (int nt = 0; nt < 4; ++nt)
                    b[nt] = wb[((t * 2 + half) * 4 + nt) * 64 + lane];
                #pragma unroll
                for (int mt = 0; mt < MT; ++mt) {
                    int idx = wv * (MT * 16) + mt * 16 + col + S + 1 + d;
                    short8 a = *(const short8*)(ls + idx * 72 + half * 32 + quad * 8);
                    bool ok = (kx == 0) ? mok0[mt] : (kx == 2) ? mok2[mt] : true;
                    if (!ok) a = (short8){0, 0, 0, 0, 0, 0, 0, 0};
                    #pragma unroll
                    for (int nt = 0; nt < 4; ++nt)
                        acc[mt][nt] = __builtin_amdgcn_mfma_f32_16x16x32_bf16(a, b[nt], acc[mt][nt], 0, 0, 0);
                }
            }
        }
    }
    float s[4] = {0.f, 0.f, 0.f, 0.f}, s2[4] = {0.f, 0.f, 0.f, 0.f};
    float* ob = out + (size_t)img * P * 64;
    #pragma unroll
    for (int mt = 0; mt < MT; ++mt) {
        int tb = p0 + wv * (MT * 16) + mt * 16 + quad * 4;
        #pragma unroll
        for (int reg = 0; reg < 4; ++reg) {
            int pr = tb + reg;
            if (pr < P) {
                #pragma unroll
                for (int nt = 0; nt < 4; ++nt) {
                    float v = acc[mt][nt][reg];
                    ob[(size_t)pr * 64 + nt * 16 + col] = v;
                    s[nt] += v;
                    s2[nt] = fmaf(v, v, s2[nt]);
                }
            }
        }
    }
    #pragma unroll
    for (int d = 16; d < 64; d <<= 1)
        #pragma unroll
        for (int nt = 0; nt < 4; ++nt) {
            s[nt] += __shfl_xor(s[nt], d, 64);
            s2[nt] += __shfl_xor(s2[nt], d, 64);
        }
    if (quad == 0) {
        #pragma unroll
        for (int nt = 0; nt < 4; ++nt) {
            qs[wv][nt * 16 + col] = s[nt];
            qs2[wv][nt * 16 + col] = s2[nt];
        }
    }
    __syncthreads();
    if (wv == 0) {
        int g = (img < NQ) ? 0 : 1 + (img - NQ) / SHOT;
        int rep = blockIdx.x & (NREP - 1);
        float ts = qs[0][lane] + qs[1][lane] + qs[2][lane] + qs[3][lane];
        float ts2 = qs2[0][lane] + qs2[1][lane] + qs2[2][lane] + qs2[3][lane];
        float* base = sums + ((size_t)(g * 64 + lane) * 2) * NREP + rep;
        atomicAdd(base, ts);
        atomicAdd(base + NREP, ts2);
    }
}

// fold (mean, invstd, gamma, beta) -> (a, b): y = x*a + b   (sums has NREP replicas)
__global__ void finalize_k(const float* __restrict__ sums, float* __restrict__ ms,
                           const float* __restrict__ gamma, const float* __restrict__ beta, int P)
{
    int i = blockIdx.x * blockDim.x + threadIdx.x;
    if (i >= 6 * 64) return;
    int g = i >> 6, c = i & 63;
    const float* ps = sums + (size_t)i * 2 * NREP;
    float s = 0.f, s2 = 0.f;
    #pragma unroll
    for (int r = 0; r < NREP; ++r) { s += ps[r]; s2 += ps[NREP + r]; }
    float cnt = (float)((g == 0 ? NQ : SHOT) * P);
    float mean = s / cnt;
    float var = s2 / cnt - mean * mean;
    float a = rsqrtf(var + EPSB) * gamma[c];
    ms[i * 2] = a;
    ms[i * 2 + 1] = fmaf(-mean, a, beta[c]);
}

// ---------------- BN + LeakyReLU + 2x2 maxpool -> bf16 ----------------
template <typename T>
__global__ __launch_bounds__(256) void bnpool_k(const T* __restrict__ x, const float* __restrict__ ms,
                                                __hip_bfloat16* __restrict__ out, int Win)
{
    int Wout = Win >> 1, Pout = Wout * Wout;
    size_t idx = (size_t)blockIdx.x * 256 + threadIdx.x;
    size_t total = (size_t)NIMG * Pout * 64;
    if (idx >= total) return;
    int c = (int)(idx & 63);
    size_t t = idx >> 6;
    int p = (int)(t % Pout);
    int img = (int)(t / Pout);
    int y = p / Wout, xo = p - y * Wout;
    int g = (img < NQ) ? 0 : 1 + (img - NQ) / SHOT;
    float a = ms[(g * 64 + c) * 2], bb = ms[(g * 64 + c) * 2 + 1];
    const T* base = x + (((size_t)img * Win + 2 * y) * Win + 2 * xo) * 64 + c;
    float mx = -3.4e38f;
    #pragma unroll
    for (int dy = 0; dy < 2; ++dy)
        #pragma unroll
        for (int dx = 0; dx < 2; ++dx) {
            float v = ldf(base + ((size_t)dy * Win + dx) * 64);
            v = fmaf(v, a, bb);
            v = v >= 0.f ? v : SLOPE * v;
            mx = fmaxf(mx, v);
        }
    out[idx] = __float2bfloat16(mx);
}

// ---------------- BN + LeakyReLU (elementwise, stage 3) -> bf16 ----------------
__global__ __launch_bounds__(256) void bnact_k(const float* __restrict__ x, const float* __restrict__ ms,
                                               __hip_bfloat16* __restrict__ out)
{
    size_t idx = (size_t)blockIdx.x * 256 + threadIdx.x;
    size_t total = (size_t)NIMG * P3 * 64;
    if (idx >= total) return;
    int c = (int)(idx & 63);
    int img = (int)(idx >> 6) / P3;
    int g = (img < NQ) ? 0 : 1 + (img - NQ) / SHOT;
    float v = fmaf(x[idx], ms[(g * 64 + c) * 2], ms[(g * 64 + c) * 2 + 1]);
    out[idx] = __float2bfloat16(v >= 0.f ? v : SLOPE * v);
}

// ---------------- BN4 + LeakyReLU + per-pixel L2-normalize -> bf16 ----------------
__global__ __launch_bounds__(256) void bnnorm_k(const float* __restrict__ x, const float* __restrict__ ms,
                                                __hip_bfloat16* __restrict__ out)
{
    int lane = threadIdx.x & 63, wvr = threadIdx.x >> 6;
    int pix = blockIdx.x * 4 + wvr;        // one wave per pixel
    if (pix >= NIMG * P3) return;
    int img = pix / P3;
    int g = (img < NQ) ? 0 : 1 + (img - NQ) / SHOT;
    float v = fmaf(x[(size_t)pix * 64 + lane], ms[(g * 64 + lane) * 2], ms[(g * 64 + lane) * 2 + 1]);
    v = v >= 0.f ? v : SLOPE * v;
    float ss = v * v;
    #pragma unroll
    for (int d = 32; d > 0; d >>= 1) ss += __shfl_xor(ss, d, 64);
    out[(size_t)pix * 64 + lane] = __float2bfloat16(v * rsqrtf(ss));
}

// ---------------- similarity: MFMA bf16, dbuf LDS pipeline, branchless top-3 ----------------
__device__ __forceinline__ void ins3(float v, float& t0, float& t1, float& t2)
{
    float n1 = __builtin_amdgcn_fmed3f(v, t0, t1);
    float n2 = __builtin_amdgcn_fmed3f(v, t1, t2);
    t0 = fmaxf(t0, v);
    t1 = n1;
    t2 = n2;
}

__global__ __launch_bounds__(256) void sim_k(const __hip_bfloat16* __restrict__ fhat,
                                             float* __restrict__ out)
{
    __shared__ __align__(16) unsigned short sl[2][128 * 72];   // dbuf, 128 m-rows, 72-ushort stride
    int t = blockIdx.x;
    int qb = t % 7;
    int n = (t / 7) % NCLS;
    int bq = t / (7 * NCLS);
    int tid = threadIdx.x, lane = tid & 63, wv = tid >> 6;
    int col = lane & 15, quad = lane >> 4;
    int q = qb * 64 + wv * 16 + col;
    int qc = q < P3 ? q : P3 - 1;
    const unsigned short* qp = (const unsigned short*)fhat + ((size_t)bq * P3 + qc) * 64;
    short8 a0 = *(const short8*)(qp + quad * 8);
    short8 a1 = *(const short8*)(qp + 32 + quad * 8);
    const unsigned short* sp = (const unsigned short*)fhat + (size_t)(NQ + n * SHOT) * P3 * 64;
    int srow = tid >> 3;                 // 0..31
    int scc = (tid & 7) * 8;
    const short8 z8 = {0, 0, 0, 0, 0, 0, 0, 0};
    float t0[4], t1[4], t2[4];
    #pragma unroll
    for (int i = 0; i < 4; ++i) { t0[i] = NEGINF; t1[i] = NEGINF; t2[i] = NEGINF; }
    // prologue: stage chunk 0
    short8 r[4];
    #pragma unroll
    for (int i = 0; i < 4; ++i) {
        int m = srow + i * 32;
        r[i] = (m < MM) ? *(const short8*)(sp + (size_t)m * 64 + scc) : z8;
    }
    #pragma unroll
    for (int i = 0; i < 4; ++i)
        *(short8*)(&sl[0][(srow + i * 32) * 72 + scc]) = r[i];
    __syncthreads();
    for (int c = 0; c < MCH; ++c) {
        int m0 = c * 128;
        if (c + 1 < MCH) {                       // prefetch next chunk into regs
            int mb = m0 + 128;
            #pragma unroll
            for (int i = 0; i < 4; ++i) {
                int m = mb + srow + i * 32;
                r[i] = (m < MM) ? *(const short8*)(sp + (size_t)m * 64 + scc) : z8;
            }
        }
        const unsigned short* sb = sl[c & 1];
        #pragma unroll
        for (int mt = 0; mt < 8; ++mt) {
            int mbase = m0 + mt * 16;
            if (mbase < MM) {                    // wave-uniform
                const unsigned short* sr = sb + (mt * 16 + col) * 72;
                short8 b0 = *(const short8*)(sr + quad * 8);
                short8 b1 = *(const short8*)(sr + 32 + quad * 8);
                f32x4 acc = {0.f, 0.f, 0.f, 0.f};
                acc = __builtin_amdgcn_mfma_f32_16x16x32_bf16(a0, b0, acc, 0, 0, 0);
                acc = __builtin_amdgcn_mfma_f32_16x16x32_bf16(a1, b1, acc, 0, 0, 0);
                if (mbase + 15 < MM) {
                    #pragma unroll
                    for (int i = 0; i < 4; ++i) ins3(acc[i], t0[i], t1[i], t2[i]);
                } else {
                    float bias = (mbase + col < MM) ? 0.f : NEGINF;
                    #pragma unroll
                    for (int i = 0; i < 4; ++i) ins3(acc[i] + bias, t0[i], t1[i], t2[i]);
                }
            }
        }
        if (c + 1 < MCH) {                       // write prefetch to other buffer
            #pragma unroll
            for (int i = 0; i < 4; ++i)
                *(short8*)(&sl[(c + 1) & 1][(srow + i * 32) * 72 + scc]) = r[i];
        }
        __syncthreads();
    }
    #pragma unroll
    for (int d = 1; d < 16; d <<= 1) {
        #pragma unroll
        for (int i = 0; i < 4; ++i) {
            float u0 = __shfl_xor(t0[i], d, 64);
            float u1 = __shfl_xor(t1[i], d, 64);
            float u2 = __shfl_xor(t2[i], d, 64);
            ins3(u0, t0[i], t1[i], t2[i]);
            ins3(u1, t0[i], t1[i], t2[i]);
            ins3(u2, t0[i], t1[i], t2[i]);
        }
    }
    if (col == 0) {
        float s = 0.f;
        int q0 = qb * 64 + wv * 16 + quad * 4;
        #pragma unroll
        for (int i = 0; i < 4; ++i)
            if (q0 + i < P3) s += t0[i] + t1[i] + t2[i];
        atomicAdd(&out[bq * NCLS + n], s);
    }
}

extern "C" void kernel_launch(void* const* d_in, const int* in_sizes, int n_in,
                              void* d_out, int out_size, void* d_ws, size_t ws_size,
                              hipStream_t stream)
{
    const float* input1 = (const float*)d_in[0];
    const float* input2 = (const float*)d_in[1];
    const float* w1 = (const float*)d_in[2];
    const float* g1 = (const float*)d_in[3];
    const float* b1 = (const float*)d_in[4];
    const float* w2 = (const float*)d_in[5];
    const float* g2 = (const float*)d_in[6];
    const float* b2 = (const float*)d_in[7];
    const float* w3 = (const float*)d_in[8];
    const float* g3 = (const float*)d_in[9];
    const float* b3 = (const float*)d_in[10];
    const float* w4 = (const float*)d_in[11];
    const float* g4 = (const float*)d_in[12];
    const float* b4 = (const float*)d_in[13];
    float* out = (float*)d_out;

    char* w8 = (char*)d_ws;
    const size_t oB = 51480576;
    const size_t oT = oB + 12870144;
    const size_t STG = 6 * 64 * 2 * NREP * sizeof(float);   // 98304 B per stage
    __hip_bfloat16* conv1raw = (__hip_bfloat16*)(w8 + 0);
    float* conv2raw = (float*)(w8 + 0);
    float* conv3raw = (float*)(w8 + 0);
    __hip_bfloat16* act3 = (__hip_bfloat16*)(w8 + 6435072);
    float* conv4raw = (float*)(w8 + 9652608);
    __hip_bfloat16* fhat = (__hip_bfloat16*)(w8 + 16087680);
    __hip_bfloat16* pooled1 = (__hip_bfloat16*)(w8 + oB);     // 12.87MB
    __hip_bfloat16* pooled2 = (__hip_bfloat16*)(w8 + oB);     // reuse (3.2MB)
    float* sums = (float*)(w8 + oT);                          // 4 stages x 98304 B
    float* ms = (float*)(w8 + oT + 4 * STG);
    unsigned short* wpk2 = (unsigned short*)(w8 + oT + 4 * STG + 12288);
    unsigned short* wpk3 = (unsigned short*)(w8 + oT + 4 * STG + 12288 + 73728);
    unsigned short* wpk4 = (unsigned short*)(w8 + oT + 4 * STG + 12288 + 147456);
    unsigned short* wpk1 = (unsigned short*)(w8 + oT + 4 * STG + 12288 + 221184);
    if (ws_size < oT + 4 * STG + 12288 + 221184 + 8192) return;
    float* sums1 = sums;
    float* sums2 = sums + 6 * 64 * 2 * NREP;
    float* sums3 = sums2 + 6 * 64 * 2 * NREP;
    float* sums4 = sums3 + 6 * 64 * 2 * NREP;

    hipMemsetAsync(d_out, 0, (size_t)out_size * sizeof(float), stream);
    hipMemsetAsync(sums, 0, 4 * STG, stream);

    pack_all_k<<<448, 256, 0, stream>>>(w1, w2, w3, w4, wpk1, wpk2, wpk3, wpk4);

    // stage 1: conv1 MFMA (+stats) -> finalize -> BN+LReLU+pool (84 -> 42)
    conv1m_k<<<NIMG * 28, 256, 0, stream>>>(input1, input2, wpk1, conv1raw, sums1);
    finalize_k<<<2, 256, 0, stream>>>(sums1, ms + 0, g1, b1, P1);
    bnpool_k<__hip_bfloat16><<<25137, 256, 0, stream>>>(conv1raw, ms + 0, pooled1, 84);
    // stage 2: conv2 MFMA (+stats) -> finalize -> BN+LReLU+pool (42 -> 21)
    conv64m_k<42, 256><<<NIMG * 7, 256, 0, stream>>>((const unsigned short*)pooled1, wpk2, conv2raw, sums2);
    finalize_k<<<2, 256, 0, stream>>>(sums2, ms + 768, g2, b2, P2);
    bnpool_k<float><<<6285, 256, 0, stream>>>(conv2raw, ms + 768, pooled2, 42);
    // stage 3: conv3 MFMA (+stats) -> finalize -> BN+LReLU
    conv64m_k<21, 128><<<NIMG * 4, 256, 0, stream>>>((const unsigned short*)pooled2, wpk3, conv3raw, sums3);
    finalize_k<<<2, 256, 0, stream>>>(sums3, ms + 1536, g3, b3, P3);
    bnact_k<<<6285, 256, 0, stream>>>(conv3raw, ms + 1536, act3);
    // stage 4: conv4 MFMA (+stats) -> finalize -> BN+LReLU+normalize -> bf16 fhat
    conv64m_k<21, 128><<<NIMG * 4, 256, 0, stream>>>((const unsigned short*)act3, wpk4, conv4raw, sums4);
    finalize_k<<<2, 256, 0, stream>>>(sums4, ms + 2304, g4, b4, P3);
    bnnorm_k<<<6285, 256, 0, stream>>>(conv4raw, ms + 2304, fhat);
    // similarity + top-3 + sum
    sim_k<<<NQ * NCLS * 7, 256, 0, stream>>>(fhat, out);
}